// Round 1
// baseline (1781.238 us; speedup 1.0000x reference)
//
#include <hip/hip_runtime.h>

static constexpr int nL = 103, nR = 512, nB = 2, nS = 512, nD = 768;
static constexpr float INV_SQRT_D = 0.03608439182435161f; // 1/sqrt(768)

// ws layout (float offsets)
static constexpr size_t OFF_MT   = 0;                          // 768*768  : MT[d1][d] = sum_j Wq[d1,j]Wk[d,j]
static constexpr size_t OFF_KQT  = OFF_MT  + (size_t)nD*nD;    // nB*nD*nS : kqT[b][d1][s]
static constexpr size_t OFF_QBK  = OFF_KQT + (size_t)nB*nD*nS; // nD       : Wq@bk
static constexpr size_t OFF_WKBQ = OFF_QBK + nD;               // nD       : Wk@bq
static constexpr size_t OFF_WV3  = OFF_WKBQ + nD;              // 3*nD     : Wv@{w_law_d,w_accu_d,w_term_d}
static constexpr size_t OFF_CST  = OFF_WV3 + 3*(size_t)nD;     // 4        : {bq.bk, bv.wld, bv.wad, bv.wtd}
static constexpr size_t OFF_C    = OFF_CST + 4;                // nB*nS    : c[b,s] = bq.facts_k
static constexpr size_t OFF_HV   = OFF_C   + (size_t)nB*nS;    // 3*nB*nS  : hv_law / hv_accu / hv_term
static constexpr size_t OFF_SUM  = OFF_HV  + 3*(size_t)nB*nS;  // 3*nB*nL  : r-reduced head partials

__device__ inline float wredsum(float v) {
#pragma unroll
  for (int o = 32; o; o >>= 1) v += __shfl_xor(v, o);
  return v;
}
__device__ inline float wredmax(float v) {
#pragma unroll
  for (int o = 32; o; o >>= 1) v = fmaxf(v, __shfl_xor(v, o));
  return v;
}

// ---- K0: small matvecs + consts -------------------------------------------
__global__ void k_vecs(const float* __restrict__ Wq, const float* __restrict__ Wk,
                       const float* __restrict__ Wv, const float* __restrict__ bq,
                       const float* __restrict__ bk, const float* __restrict__ bv,
                       const float* __restrict__ wld, const float* __restrict__ wad,
                       const float* __restrict__ wtd, float* __restrict__ ws) {
  int lane = threadIdx.x;
  if (blockIdx.x < 12) {
    int d = blockIdx.x * 64 + lane;
    const float* wqr = Wq + (size_t)d * nD;
    const float* wkr = Wk + (size_t)d * nD;
    const float* wvr = Wv + (size_t)d * nD;
    float q = 0.f, k = 0.f, a0 = 0.f, a1 = 0.f, a2 = 0.f;
    for (int j = 0; j < nD; j += 4) {
      float4 q4 = *(const float4*)(wqr + j);
      float4 k4 = *(const float4*)(wkr + j);
      float4 v4 = *(const float4*)(wvr + j);
      float4 bk4 = *(const float4*)(bk + j);
      float4 bq4 = *(const float4*)(bq + j);
      float4 l4 = *(const float4*)(wld + j);
      float4 a4 = *(const float4*)(wad + j);
      float4 t4 = *(const float4*)(wtd + j);
      q  += q4.x*bk4.x + q4.y*bk4.y + q4.z*bk4.z + q4.w*bk4.w;
      k  += k4.x*bq4.x + k4.y*bq4.y + k4.z*bq4.z + k4.w*bq4.w;
      a0 += v4.x*l4.x + v4.y*l4.y + v4.z*l4.z + v4.w*l4.w;
      a1 += v4.x*a4.x + v4.y*a4.y + v4.z*a4.z + v4.w*a4.w;
      a2 += v4.x*t4.x + v4.y*t4.y + v4.z*t4.z + v4.w*t4.w;
    }
    ws[OFF_QBK + d]  = q;
    ws[OFF_WKBQ + d] = k;
    ws[OFF_WV3 + d]        = a0;
    ws[OFF_WV3 + nD + d]   = a1;
    ws[OFF_WV3 + 2*nD + d] = a2;
  } else {
    float c0 = 0.f, c1 = 0.f, c2 = 0.f, c3 = 0.f;
    for (int j = lane; j < nD; j += 64) {
      c0 += bq[j]*bk[j]; c1 += bv[j]*wld[j]; c2 += bv[j]*wad[j]; c3 += bv[j]*wtd[j];
    }
    c0 = wredsum(c0); c1 = wredsum(c1); c2 = wredsum(c2); c3 = wredsum(c3);
    if (lane == 0) {
      ws[OFF_CST+0] = c0; ws[OFF_CST+1] = c1; ws[OFF_CST+2] = c2; ws[OFF_CST+3] = c3;
    }
  }
}

// ---- NT GEMM: C[m,n] = sum_k A[m,k]*B[n,k] (+bias[m]); 64x64 tile ----------
__global__ __launch_bounds__(256) void mm_nt(const float* __restrict__ A,
                                             const float* __restrict__ Bm,
                                             float* __restrict__ C,
                                             const float* __restrict__ bias,
                                             int M, int N, int K, long sB, long sC) {
  __shared__ float Ast[16][68];  // [k][m], +4 pad keeps b128 reads aligned
  __shared__ float Bst[16][68];  // [k][n]
  const float* Bp = Bm + (size_t)blockIdx.z * sB;
  float* Cp = C + (size_t)blockIdx.z * sC;
  int m0 = blockIdx.y * 64, n0 = blockIdx.x * 64;
  int tid = threadIdx.x;
  int tx = tid & 15, ty = tid >> 4;
  int li = (tid * 4) >> 4;     // 0..63
  int lj = (tid * 4) & 15;     // 0,4,8,12
  float acc[4][4] = {};
  for (int k0 = 0; k0 < K; k0 += 16) {
    float4 a4 = *(const float4*)(A  + (size_t)(m0 + li) * K + k0 + lj);
    float4 b4 = *(const float4*)(Bp + (size_t)(n0 + li) * K + k0 + lj);
    __syncthreads();
    Ast[lj+0][li] = a4.x; Ast[lj+1][li] = a4.y; Ast[lj+2][li] = a4.z; Ast[lj+3][li] = a4.w;
    Bst[lj+0][li] = b4.x; Bst[lj+1][li] = b4.y; Bst[lj+2][li] = b4.z; Bst[lj+3][li] = b4.w;
    __syncthreads();
#pragma unroll
    for (int kk = 0; kk < 16; ++kk) {
      float4 av4 = *(const float4*)&Ast[kk][ty * 4];
      float4 bv4 = *(const float4*)&Bst[kk][tx * 4];
      float av[4] = {av4.x, av4.y, av4.z, av4.w};
      float bv[4] = {bv4.x, bv4.y, bv4.z, bv4.w};
#pragma unroll
      for (int mi = 0; mi < 4; ++mi)
#pragma unroll
        for (int ni = 0; ni < 4; ++ni) acc[mi][ni] += av[mi] * bv[ni];
    }
  }
#pragma unroll
  for (int mi = 0; mi < 4; ++mi) {
    int m = m0 + ty * 4 + mi;
    float bb = bias ? bias[m] : 0.0f;
#pragma unroll
    for (int ni = 0; ni < 4; ++ni)
      Cp[(size_t)m * N + n0 + tx * 4 + ni] = acc[mi][ni] + bb;
  }
}

// ---- K2: per-(b,s) scalars c, hv_law/accu/term -----------------------------
__global__ void k_chv(const float* __restrict__ outp, float* __restrict__ ws) {
  int bs = blockIdx.x;
  int lane = threadIdx.x;
  const float* row = outp + (size_t)bs * nD;
  const float* wkbq = ws + OFF_WKBQ;
  const float* wv0 = ws + OFF_WV3;
  const float* wv1 = ws + OFF_WV3 + nD;
  const float* wv2 = ws + OFF_WV3 + 2*nD;
  float a0 = 0.f, a1 = 0.f, a2 = 0.f, a3 = 0.f;
  for (int d = lane * 4; d < nD; d += 256) {
    float4 o4 = *(const float4*)(row + d);
    float4 k4 = *(const float4*)(wkbq + d);
    float4 l4 = *(const float4*)(wv0 + d);
    float4 c4 = *(const float4*)(wv1 + d);
    float4 t4 = *(const float4*)(wv2 + d);
    a0 += o4.x*k4.x + o4.y*k4.y + o4.z*k4.z + o4.w*k4.w;
    a1 += o4.x*l4.x + o4.y*l4.y + o4.z*l4.z + o4.w*l4.w;
    a2 += o4.x*c4.x + o4.y*c4.y + o4.z*c4.z + o4.w*c4.w;
    a3 += o4.x*t4.x + o4.y*t4.y + o4.z*t4.z + o4.w*t4.w;
  }
  a0 = wredsum(a0); a1 = wredsum(a1); a2 = wredsum(a2); a3 = wredsum(a3);
  if (lane == 0) {
    ws[OFF_C + bs]             = a0 + ws[OFF_CST+0];
    ws[OFF_HV + bs]            = a1 + ws[OFF_CST+1];
    ws[OFF_HV + nB*nS + bs]    = a2 + ws[OFF_CST+2];
    ws[OFF_HV + 2*nB*nS + bs]  = a3 + ws[OFF_CST+3];
  }
}

// ---- K3: fused scores -> softmax -> head dots -> tanh -> r-partials --------
__global__ __launch_bounds__(256) void k_attn(const float* __restrict__ laws,
                                              const int* __restrict__ mask,
                                              float* __restrict__ ws,
                                              const float* __restrict__ bld,
                                              const float* __restrict__ wl1,
                                              const float* __restrict__ bad,
                                              const float* __restrict__ wa1,
                                              const float* __restrict__ btd,
                                              const float* __restrict__ wt1) {
  __shared__ float laws_s[16 * nD];
  __shared__ float redA[4];
  __shared__ float redB[4][4];
  int tid = threadIdx.x;
  int lane = tid & 63, wid = tid >> 6;
  int rt = blockIdx.x, b = blockIdx.y, l = blockIdx.z;

  const float* lp = laws + ((size_t)l * nR + (size_t)rt * 16) * nD;
  for (int i = tid * 4; i < 16 * nD; i += 256 * 4)
    *(float4*)&laws_s[i] = *(const float4*)(lp + i);

  int s0 = tid, s1 = tid + 256;
  const float* cp  = ws + OFF_C + (size_t)b * nS;
  const float* hlp = ws + OFF_HV + (size_t)b * nS;
  const float* hap = ws + OFF_HV + (size_t)nB * nS + (size_t)b * nS;
  const float* htp = ws + OFF_HV + 2 * (size_t)nB * nS + (size_t)b * nS;
  float cc0 = cp[s0], cc1 = cp[s1];
  float hl0 = hlp[s0], hl1 = hlp[s1];
  float ha0 = hap[s0], ha1 = hap[s1];
  float ht0 = htp[s0], ht1 = htp[s1];
  float ma0 = (1.0f - (float)mask[b * nS + s0]) * -10000.0f;
  float ma1 = (1.0f - (float)mask[b * nS + s1]) * -10000.0f;
  __syncthreads();

  float acc[16][2] = {};
  const float* kq = ws + OFF_KQT + (size_t)b * nD * nS;
  for (int d = 0; d < nD; d += 4) {
    const float* kr = kq + (size_t)d * nS;
    float kv00 = kr[s0],          kv01 = kr[s1];
    float kv10 = kr[nS + s0],     kv11 = kr[nS + s1];
    float kv20 = kr[2*nS + s0],   kv21 = kr[2*nS + s1];
    float kv30 = kr[3*nS + s0],   kv31 = kr[3*nS + s1];
#pragma unroll
    for (int r = 0; r < 16; ++r) {
      float4 lw = *(const float4*)&laws_s[r * nD + d];
      acc[r][0] += lw.x*kv00 + lw.y*kv10 + lw.z*kv20 + lw.w*kv30;
      acc[r][1] += lw.x*kv01 + lw.y*kv11 + lw.z*kv21 + lw.w*kv31;
    }
  }

  float vbld = bld[0], vbad = bad[0], vbtd = btd[0];
  float lacc = 0.f, aacc = 0.f, tacc = 0.f;
  for (int r = 0; r < 16; ++r) {
    float l0 = (acc[r][0] + cc0) * INV_SQRT_D + ma0;
    float l1 = (acc[r][1] + cc1) * INV_SQRT_D + ma1;
    float m = wredmax(fmaxf(l0, l1));
    if (lane == 0) redA[wid] = m;
    __syncthreads();
    m = fmaxf(fmaxf(redA[0], redA[1]), fmaxf(redA[2], redA[3]));
    float e0 = __expf(l0 - m), e1 = __expf(l1 - m);
    float se = wredsum(e0 + e1);
    float pl = wredsum(e0 * hl0 + e1 * hl1);
    float pa = wredsum(e0 * ha0 + e1 * ha1);
    float pt = wredsum(e0 * ht0 + e1 * ht1);
    if (lane == 0) { redB[wid][0] = se; redB[wid][1] = pl; redB[wid][2] = pa; redB[wid][3] = pt; }
    __syncthreads();
    if (tid == 0) {
      float SE = redB[0][0] + redB[1][0] + redB[2][0] + redB[3][0];
      float PL = redB[0][1] + redB[1][1] + redB[2][1] + redB[3][1];
      float PA = redB[0][2] + redB[1][2] + redB[2][2] + redB[3][2];
      float PT = redB[0][3] + redB[1][3] + redB[2][3] + redB[3][3];
      float inv = 1.0f / SE;
      int rr = rt * 16 + r;
      lacc += tanhf(PL * inv + vbld) * wl1[rr];
      aacc += tanhf(PA * inv + vbad) * wa1[rr];
      tacc += tanhf(PT * inv + vbtd) * wt1[rr];
    }
  }
  if (tid == 0) {
    float* sums = ws + OFF_SUM;
    atomicAdd(&sums[b * nL + l], lacc);
    atomicAdd(&sums[nB * nL + b * nL + l], aacc);
    atomicAdd(&sums[2 * nB * nL + b * nL + l], tacc);
  }
}

// ---- K4: finalize heads ----------------------------------------------------
__global__ void k_final(const float* __restrict__ ws, float* __restrict__ out,
                        const float* __restrict__ bl1, const float* __restrict__ ba1,
                        const float* __restrict__ Wa2, const float* __restrict__ ba2,
                        const float* __restrict__ bt1, const float* __restrict__ Wt2,
                        const float* __restrict__ bt2) {
  __shared__ float abl[nB * nL], tbl[nB * nL];
  int t = threadIdx.x;
  const float* sl = ws + OFF_SUM;
  const float* sa = sl + nB * nL;
  const float* st = sa + nB * nL;
  if (t < nB * nL) {
    out[t] = sl[t] + bl1[0];
    abl[t] = tanhf(sa[t] + ba1[0]);
    tbl[t] = tanhf(st[t] + bt1[0]);
  }
  __syncthreads();
  for (int idx = t; idx < nB * 119; idx += 256) {
    int b = idx / 119, j = idx % 119;
    float a = ba2[j];
    for (int ll = 0; ll < nL; ++ll) a += Wa2[j * nL + ll] * abl[b * nL + ll];
    out[nB * nL + idx] = a;
  }
  for (int idx = t; idx < nB * 11; idx += 256) {
    int b = idx / 11, j = idx % 11;
    float a = bt2[j];
    for (int ll = 0; ll < nL; ++ll) a += Wt2[j * nL + ll] * tbl[b * nL + ll];
    out[nB * nL + nB * 119 + idx] = a;
  }
}

extern "C" void kernel_launch(void* const* d_in, const int* in_sizes, int n_in,
                              void* d_out, int out_size, void* d_ws, size_t ws_size,
                              hipStream_t stream) {
  (void)in_sizes; (void)n_in; (void)out_size; (void)ws_size;
  const float* outp = (const float*)d_in[0];
  const int*   mask = (const int*)d_in[1];
  const float* laws = (const float*)d_in[2];
  const float* Wq = (const float*)d_in[3];  const float* bq = (const float*)d_in[4];
  const float* Wk = (const float*)d_in[5];  const float* bk = (const float*)d_in[6];
  const float* Wv = (const float*)d_in[7];  const float* bv = (const float*)d_in[8];
  const float* wld = (const float*)d_in[9];  const float* bld = (const float*)d_in[10];
  const float* wl1 = (const float*)d_in[11]; const float* bl1 = (const float*)d_in[12];
  const float* wad = (const float*)d_in[13]; const float* bad = (const float*)d_in[14];
  const float* wa1 = (const float*)d_in[15]; const float* ba1 = (const float*)d_in[16];
  const float* Wa2 = (const float*)d_in[17]; const float* ba2 = (const float*)d_in[18];
  const float* wtd = (const float*)d_in[19]; const float* btd = (const float*)d_in[20];
  const float* wt1 = (const float*)d_in[21]; const float* bt1 = (const float*)d_in[22];
  const float* Wt2 = (const float*)d_in[23]; const float* bt2 = (const float*)d_in[24];
  float* ws = (float*)d_ws;
  float* fout = (float*)d_out;

  hipMemsetAsync((void*)(ws + OFF_SUM), 0, 3 * nB * nL * sizeof(float), stream);
  k_vecs<<<13, 64, 0, stream>>>(Wq, Wk, Wv, bq, bk, bv, wld, wad, wtd, ws);
  // MT[d1][d] = sum_j Wq[d1,j] Wk[d,j]
  mm_nt<<<dim3(12, 12, 1), 256, 0, stream>>>(Wq, Wk, ws + OFF_MT, nullptr,
                                             nD, nD, nD, 0, 0);
  // kqT[b][d1][s] = sum_d MT[d1,d] * out[b,s,d] + qbk[d1]
  mm_nt<<<dim3(8, 12, nB), 256, 0, stream>>>(ws + OFF_MT, outp, ws + OFF_KQT,
                                             ws + OFF_QBK, nD, nS, nD,
                                             (long)nS * nD, (long)nD * nS);
  k_chv<<<nB * nS, 64, 0, stream>>>(outp, ws);
  k_attn<<<dim3(nR / 16, nB, nL), 256, 0, stream>>>(laws, mask, ws,
                                                    bld, wl1, bad, wa1, btd, wt1);
  k_final<<<1, 256, 0, stream>>>(ws, fout, bl1, ba1, Wa2, ba2, bt1, Wt2, bt2);
}

// Round 2
// 632.618 us; speedup vs baseline: 2.8157x; 2.8157x over previous
//
#include <hip/hip_runtime.h>

static constexpr int nL = 103, nR = 512, nB = 2, nS = 512, nD = 768;
static constexpr float INV_SQRT_D = 0.03608439182435161f; // 1/sqrt(768)

typedef short bf16x8 __attribute__((ext_vector_type(8)));
typedef float f32x4 __attribute__((ext_vector_type(4)));
typedef unsigned short ushort4v __attribute__((ext_vector_type(4)));
typedef unsigned short ushort8v __attribute__((ext_vector_type(8)));

// ws layout (float offsets). kqB (bf16 frag layout, 1.5MB) aliases MT (2.25MB):
// MT is only needed until the kqT GEMM finishes; k_pack then overwrites it.
static constexpr size_t OFF_MT   = 0;                          // 768*768  : MT[d1][d] = sum_j Wq[d1,j]Wk[d,j]
static constexpr size_t OFF_KQB  = OFF_MT;                     // 96*1024*8 ushorts (bf16 B-fragments)
static constexpr size_t OFF_KQT  = OFF_MT  + (size_t)nD*nD;    // nB*nD*nS : kqT[b][d1][s] fp32
static constexpr size_t OFF_QBK  = OFF_KQT + (size_t)nB*nD*nS; // nD       : Wq@bk
static constexpr size_t OFF_WKBQ = OFF_QBK + nD;               // nD       : Wk@bq
static constexpr size_t OFF_WV3  = OFF_WKBQ + nD;              // 3*nD     : Wv@{w_law_d,w_accu_d,w_term_d}
static constexpr size_t OFF_CST  = OFF_WV3 + 3*(size_t)nD;     // 4        : {bq.bk, bv.wld, bv.wad, bv.wtd}
static constexpr size_t OFF_C    = OFF_CST + 4;                // nB*nS    : c[b,s] = bq.facts_k (+const)
static constexpr size_t OFF_HV   = OFF_C   + (size_t)nB*nS;    // 3*nB*nS  : hv_law / hv_accu / hv_term
static constexpr size_t OFF_SUM  = OFF_HV  + 3*(size_t)nB*nS;  // 3*nB*nL  : r-reduced head partials

__device__ inline float wredsum(float v) {
#pragma unroll
  for (int o = 32; o; o >>= 1) v += __shfl_xor(v, o);
  return v;
}

__device__ inline unsigned short f2bf(float f) {  // RNE fp32 -> bf16
  unsigned u = __builtin_bit_cast(unsigned, f);
  u += 0x7FFFu + ((u >> 16) & 1u);
  return (unsigned short)(u >> 16);
}

// ---- K0: small matvecs + consts -------------------------------------------
__global__ void k_vecs(const float* __restrict__ Wq, const float* __restrict__ Wk,
                       const float* __restrict__ Wv, const float* __restrict__ bq,
                       const float* __restrict__ bk, const float* __restrict__ bv,
                       const float* __restrict__ wld, const float* __restrict__ wad,
                       const float* __restrict__ wtd, float* __restrict__ ws) {
  int lane = threadIdx.x;
  if (blockIdx.x < 12) {
    int d = blockIdx.x * 64 + lane;
    const float* wqr = Wq + (size_t)d * nD;
    const float* wkr = Wk + (size_t)d * nD;
    const float* wvr = Wv + (size_t)d * nD;
    float q = 0.f, k = 0.f, a0 = 0.f, a1 = 0.f, a2 = 0.f;
    for (int j = 0; j < nD; j += 4) {
      float4 q4 = *(const float4*)(wqr + j);
      float4 k4 = *(const float4*)(wkr + j);
      float4 v4 = *(const float4*)(wvr + j);
      float4 bk4 = *(const float4*)(bk + j);
      float4 bq4 = *(const float4*)(bq + j);
      float4 l4 = *(const float4*)(wld + j);
      float4 a4 = *(const float4*)(wad + j);
      float4 t4 = *(const float4*)(wtd + j);
      q  += q4.x*bk4.x + q4.y*bk4.y + q4.z*bk4.z + q4.w*bk4.w;
      k  += k4.x*bq4.x + k4.y*bq4.y + k4.z*bq4.z + k4.w*bq4.w;
      a0 += v4.x*l4.x + v4.y*l4.y + v4.z*l4.z + v4.w*l4.w;
      a1 += v4.x*a4.x + v4.y*a4.y + v4.z*a4.z + v4.w*a4.w;
      a2 += v4.x*t4.x + v4.y*t4.y + v4.z*t4.z + v4.w*t4.w;
    }
    ws[OFF_QBK + d]  = q;
    ws[OFF_WKBQ + d] = k;
    ws[OFF_WV3 + d]        = a0;
    ws[OFF_WV3 + nD + d]   = a1;
    ws[OFF_WV3 + 2*nD + d] = a2;
  } else {
    float c0 = 0.f, c1 = 0.f, c2 = 0.f, c3 = 0.f;
    for (int j = lane; j < nD; j += 64) {
      c0 += bq[j]*bk[j]; c1 += bv[j]*wld[j]; c2 += bv[j]*wad[j]; c3 += bv[j]*wtd[j];
    }
    c0 = wredsum(c0); c1 = wredsum(c1); c2 = wredsum(c2); c3 = wredsum(c3);
    if (lane == 0) {
      ws[OFF_CST+0] = c0; ws[OFF_CST+1] = c1; ws[OFF_CST+2] = c2; ws[OFF_CST+3] = c3;
    }
  }
}

// ---- NT GEMM: C[m,n] = sum_k A[m,k]*B[n,k] (+bias[m]); 64x64 tile ----------
__global__ __launch_bounds__(256) void mm_nt(const float* __restrict__ A,
                                             const float* __restrict__ Bm,
                                             float* __restrict__ C,
                                             const float* __restrict__ bias,
                                             int M, int N, int K, long sB, long sC) {
  __shared__ float Ast[16][68];
  __shared__ float Bst[16][68];
  const float* Bp = Bm + (size_t)blockIdx.z * sB;
  float* Cp = C + (size_t)blockIdx.z * sC;
  int m0 = blockIdx.y * 64, n0 = blockIdx.x * 64;
  int tid = threadIdx.x;
  int tx = tid & 15, ty = tid >> 4;
  int li = (tid * 4) >> 4;
  int lj = (tid * 4) & 15;
  float acc[4][4] = {};
  for (int k0 = 0; k0 < K; k0 += 16) {
    float4 a4 = *(const float4*)(A  + (size_t)(m0 + li) * K + k0 + lj);
    float4 b4 = *(const float4*)(Bp + (size_t)(n0 + li) * K + k0 + lj);
    __syncthreads();
    Ast[lj+0][li] = a4.x; Ast[lj+1][li] = a4.y; Ast[lj+2][li] = a4.z; Ast[lj+3][li] = a4.w;
    Bst[lj+0][li] = b4.x; Bst[lj+1][li] = b4.y; Bst[lj+2][li] = b4.z; Bst[lj+3][li] = b4.w;
    __syncthreads();
#pragma unroll
    for (int kk = 0; kk < 16; ++kk) {
      float4 av4 = *(const float4*)&Ast[kk][ty * 4];
      float4 bv4 = *(const float4*)&Bst[kk][tx * 4];
      float av[4] = {av4.x, av4.y, av4.z, av4.w};
      float bv[4] = {bv4.x, bv4.y, bv4.z, bv4.w};
#pragma unroll
      for (int mi = 0; mi < 4; ++mi)
#pragma unroll
        for (int ni = 0; ni < 4; ++ni) acc[mi][ni] += av[mi] * bv[ni];
    }
  }
#pragma unroll
  for (int mi = 0; mi < 4; ++mi) {
    int m = m0 + ty * 4 + mi;
    float bb = bias ? bias[m] : 0.0f;
#pragma unroll
    for (int ni = 0; ni < 4; ++ni)
      Cp[(size_t)m * N + n0 + tx * 4 + ni] = acc[mi][ni] + bb;
  }
}

// ---- K1b: pack kqT fp32 [b][d][s] -> bf16 B-fragment layout ----------------
// kqB[g][n][j] : g=d>>3 (96), n=b*512+s (1024), j=d&7 (8). One lane = 16B store.
__global__ void k_pack(const float* __restrict__ kqt, unsigned short* __restrict__ kqB) {
  int n = blockIdx.x * 256 + threadIdx.x;  // grid.x = 4
  int g = blockIdx.y;                       // 0..95
  int b = n >> 9, s = n & 511;
  const float* src = kqt + (size_t)b * nD * nS + (size_t)g * 8 * nS + s;
  ushort8v o;
#pragma unroll
  for (int j = 0; j < 8; ++j) o[j] = f2bf(src[(size_t)j * nS]);
  *(ushort8v*)(kqB + ((size_t)g * 1024 + n) * 8) = o;
}

// ---- K2: per-(b,s) scalars c, hv_law/accu/term -----------------------------
__global__ void k_chv(const float* __restrict__ outp, float* __restrict__ ws) {
  int bs = blockIdx.x;
  int lane = threadIdx.x;
  const float* row = outp + (size_t)bs * nD;
  const float* wkbq = ws + OFF_WKBQ;
  const float* wv0 = ws + OFF_WV3;
  const float* wv1 = ws + OFF_WV3 + nD;
  const float* wv2 = ws + OFF_WV3 + 2*nD;
  float a0 = 0.f, a1 = 0.f, a2 = 0.f, a3 = 0.f;
  for (int d = lane * 4; d < nD; d += 256) {
    float4 o4 = *(const float4*)(row + d);
    float4 k4 = *(const float4*)(wkbq + d);
    float4 l4 = *(const float4*)(wv0 + d);
    float4 c4 = *(const float4*)(wv1 + d);
    float4 t4 = *(const float4*)(wv2 + d);
    a0 += o4.x*k4.x + o4.y*k4.y + o4.z*k4.z + o4.w*k4.w;
    a1 += o4.x*l4.x + o4.y*l4.y + o4.z*l4.z + o4.w*l4.w;
    a2 += o4.x*c4.x + o4.y*c4.y + o4.z*c4.z + o4.w*c4.w;
    a3 += o4.x*t4.x + o4.y*t4.y + o4.z*t4.z + o4.w*t4.w;
  }
  a0 = wredsum(a0); a1 = wredsum(a1); a2 = wredsum(a2); a3 = wredsum(a3);
  if (lane == 0) {
    ws[OFF_C + bs]             = a0 + ws[OFF_CST+0];
    ws[OFF_HV + bs]            = a1 + ws[OFF_CST+1];
    ws[OFF_HV + nB*nS + bs]    = a2 + ws[OFF_CST+2];
    ws[OFF_HV + 2*nB*nS + bs]  = a3 + ws[OFF_CST+3];
  }
}

// ---- K3: MFMA scores -> register softmax -> head dots -> r-partials --------
// block = (r-tile of 32, b, l); wave w owns all 32 rows x cols [w*128, w*128+128)
__global__ __launch_bounds__(256, 3) void k_attn(
    const float* __restrict__ laws, const unsigned short* __restrict__ kqB,
    const int* __restrict__ mask, float* __restrict__ ws,
    const float* __restrict__ bld, const float* __restrict__ wl1,
    const float* __restrict__ bad, const float* __restrict__ wa1,
    const float* __restrict__ btd, const float* __restrict__ wt1) {
  __shared__ unsigned short laws_s[32 * 776];  // bf16, rows padded +8 (16B-aligned rows)
  __shared__ float redM[4][32];
  __shared__ float redS[4][32][4];
  const int tid = threadIdx.x;
  const int lane = tid & 63, w = tid >> 6;
  const int c = lane & 15, q = lane >> 4;
  const int bx = blockIdx.x, b = blockIdx.y, l = blockIdx.z;

  // stage laws tile (32 x 768) as bf16 into LDS (A-operand rows)
  const float* lp = laws + ((size_t)l * nR + (size_t)bx * 32) * nD;
  for (int i = tid * 4; i < 32 * nD; i += 1024) {
    int m = i / nD, d = i - m * nD;
    float4 v = *(const float4*)(lp + i);
    ushort4v u;
    u[0] = f2bf(v.x); u[1] = f2bf(v.y); u[2] = f2bf(v.z); u[3] = f2bf(v.w);
    *(ushort4v*)&laws_s[m * 776 + d] = u;
  }
  __syncthreads();

  // ---- MFMA K-loop: 24 k-tiles of 32; per wave 2 row-tiles x 8 col-tiles ---
  f32x4 acc[2][8];
#pragma unroll
  for (int rt = 0; rt < 2; ++rt)
#pragma unroll
    for (int t = 0; t < 8; ++t) acc[rt][t] = (f32x4){0.f, 0.f, 0.f, 0.f};

  const unsigned short* Bbase = kqB + ((size_t)q * 1024 + (size_t)b * 512 + w * 128 + c) * 8;
  for (int kt = 0; kt < 24; ++kt) {
    bf16x8 a0 = *(const bf16x8*)&laws_s[c * 776 + kt * 32 + q * 8];
    bf16x8 a1 = *(const bf16x8*)&laws_s[(16 + c) * 776 + kt * 32 + q * 8];
    bf16x8 bfr[8];
#pragma unroll
    for (int t = 0; t < 8; ++t)
      bfr[t] = *(const bf16x8*)(Bbase + ((size_t)kt * 4096 + t * 16) * 8);
#pragma unroll
    for (int t = 0; t < 8; ++t) {
      acc[0][t] = __builtin_amdgcn_mfma_f32_16x16x32_bf16(a0, bfr[t], acc[0][t], 0, 0, 0);
      acc[1][t] = __builtin_amdgcn_mfma_f32_16x16x32_bf16(a1, bfr[t], acc[1][t], 0, 0, 0);
    }
  }

  // ---- per-column scalars (col s = w*128 + t*16 + c) -----------------------
  const float* cp  = ws + OFF_C + (size_t)b * nS;
  const float* hlp = ws + OFF_HV + (size_t)b * nS;
  const float* hap = ws + OFF_HV + (size_t)nB * nS + (size_t)b * nS;
  const float* htp = ws + OFF_HV + 2 * (size_t)nB * nS + (size_t)b * nS;
  float cc[8], hl[8], ha[8], ht[8], ma[8];
#pragma unroll
  for (int t = 0; t < 8; ++t) {
    int s = w * 128 + t * 16 + c;
    cc[t] = cp[s]; hl[t] = hlp[s]; ha[t] = hap[s]; ht[t] = htp[s];
    ma[t] = (1.0f - (float)mask[b * nS + s]) * -10000.0f;
  }

  // logits (in-place): D row = rt*16 + q*4 + reg, col = w*128 + t*16 + c
#pragma unroll
  for (int rt = 0; rt < 2; ++rt)
#pragma unroll
    for (int t = 0; t < 8; ++t)
      acc[rt][t] = (acc[rt][t] + cc[t]) * INV_SQRT_D + ma[t];

  // ---- row max: per lane over t, then over 16 cols (shfl), then 4 waves ----
  float mx[2][4];
#pragma unroll
  for (int rt = 0; rt < 2; ++rt)
#pragma unroll
    for (int reg = 0; reg < 4; ++reg) {
      float m = acc[rt][0][reg];
#pragma unroll
      for (int t = 1; t < 8; ++t) m = fmaxf(m, acc[rt][t][reg]);
#pragma unroll
      for (int o = 1; o < 16; o <<= 1) m = fmaxf(m, __shfl_xor(m, o));
      mx[rt][reg] = m;
    }
  if (c == 0) {
#pragma unroll
    for (int rt = 0; rt < 2; ++rt)
#pragma unroll
      for (int reg = 0; reg < 4; ++reg)
        redM[w][rt * 16 + q * 4 + reg] = mx[rt][reg];
  }
  __syncthreads();
  float mf[2][4];
#pragma unroll
  for (int rt = 0; rt < 2; ++rt)
#pragma unroll
    for (int reg = 0; reg < 4; ++reg) {
      int row = rt * 16 + q * 4 + reg;
      mf[rt][reg] = fmaxf(fmaxf(redM[0][row], redM[1][row]),
                          fmaxf(redM[2][row], redM[3][row]));
    }

  // ---- exp + 4 weighted row-sums (se, pl, pa, pt) --------------------------
  float se[2][4] = {}, pl[2][4] = {}, pa[2][4] = {}, pt[2][4] = {};
#pragma unroll
  for (int rt = 0; rt < 2; ++rt)
#pragma unroll
    for (int t = 0; t < 8; ++t) {
      f32x4 v = acc[rt][t];
#pragma unroll
      for (int reg = 0; reg < 4; ++reg) {
        float e = __expf(v[reg] - mf[rt][reg]);
        se[rt][reg] += e;
        pl[rt][reg] += e * hl[t];
        pa[rt][reg] += e * ha[t];
        pt[rt][reg] += e * ht[t];
      }
    }
#pragma unroll
  for (int rt = 0; rt < 2; ++rt)
#pragma unroll
    for (int reg = 0; reg < 4; ++reg)
#pragma unroll
      for (int o = 1; o < 16; o <<= 1) {
        se[rt][reg] += __shfl_xor(se[rt][reg], o);
        pl[rt][reg] += __shfl_xor(pl[rt][reg], o);
        pa[rt][reg] += __shfl_xor(pa[rt][reg], o);
        pt[rt][reg] += __shfl_xor(pt[rt][reg], o);
      }
  if (c == 0) {
#pragma unroll
    for (int rt = 0; rt < 2; ++rt)
#pragma unroll
      for (int reg = 0; reg < 4; ++reg) {
        int row = rt * 16 + q * 4 + reg;
        redS[w][row][0] = se[rt][reg];
        redS[w][row][1] = pl[rt][reg];
        redS[w][row][2] = pa[rt][reg];
        redS[w][row][3] = pt[rt][reg];
      }
  }
  __syncthreads();

  // ---- finalize on wave 0: lane = row*2 + pair -----------------------------
  if (w == 0) {
    int row = lane >> 1, pair = lane & 1;
    float v0 = redS[0][row][pair * 2]     + redS[1][row][pair * 2]
             + redS[2][row][pair * 2]     + redS[3][row][pair * 2];
    float v1 = redS[0][row][pair * 2 + 1] + redS[1][row][pair * 2 + 1]
             + redS[2][row][pair * 2 + 1] + redS[3][row][pair * 2 + 1];
    float partner0 = __shfl_xor(v0, 1);
    float sev = pair ? partner0 : v0;
    float inv = 1.0f / sev;
    int r = bx * 32 + row;
    float cl = 0.f, ca = 0.f, ct = 0.f;
    if (pair == 0) {
      cl = tanhf(v1 * inv + bld[0]) * wl1[r];
    } else {
      ca = tanhf(v0 * inv + bad[0]) * wa1[r];
      ct = tanhf(v1 * inv + btd[0]) * wt1[r];
    }
#pragma unroll
    for (int o = 1; o < 64; o <<= 1) {
      cl += __shfl_xor(cl, o);
      ca += __shfl_xor(ca, o);
      ct += __shfl_xor(ct, o);
    }
    if (lane == 0) {
      float* sums = ws + OFF_SUM;
      atomicAdd(&sums[b * nL + l], cl);
      atomicAdd(&sums[nB * nL + b * nL + l], ca);
      atomicAdd(&sums[2 * nB * nL + b * nL + l], ct);
    }
  }
}

// ---- K4: finalize heads ----------------------------------------------------
__global__ void k_final(const float* __restrict__ ws, float* __restrict__ out,
                        const float* __restrict__ bl1, const float* __restrict__ ba1,
                        const float* __restrict__ Wa2, const float* __restrict__ ba2,
                        const float* __restrict__ bt1, const float* __restrict__ Wt2,
                        const float* __restrict__ bt2) {
  __shared__ float abl[nB * nL], tbl[nB * nL];
  int t = threadIdx.x;
  const float* sl = ws + OFF_SUM;
  const float* sa = sl + nB * nL;
  const float* st = sa + nB * nL;
  if (t < nB * nL) {
    out[t] = sl[t] + bl1[0];
    abl[t] = tanhf(sa[t] + ba1[0]);
    tbl[t] = tanhf(st[t] + bt1[0]);
  }
  __syncthreads();
  for (int idx = t; idx < nB * 119; idx += 256) {
    int b = idx / 119, j = idx % 119;
    float a = ba2[j];
    for (int ll = 0; ll < nL; ++ll) a += Wa2[j * nL + ll] * abl[b * nL + ll];
    out[nB * nL + idx] = a;
  }
  for (int idx = t; idx < nB * 11; idx += 256) {
    int b = idx / 11, j = idx % 11;
    float a = bt2[j];
    for (int ll = 0; ll < nL; ++ll) a += Wt2[j * nL + ll] * tbl[b * nL + ll];
    out[nB * nL + nB * 119 + idx] = a;
  }
}

extern "C" void kernel_launch(void* const* d_in, const int* in_sizes, int n_in,
                              void* d_out, int out_size, void* d_ws, size_t ws_size,
                              hipStream_t stream) {
  (void)in_sizes; (void)n_in; (void)out_size; (void)ws_size;
  const float* outp = (const float*)d_in[0];
  const int*   mask = (const int*)d_in[1];
  const float* laws = (const float*)d_in[2];
  const float* Wq = (const float*)d_in[3];  const float* bq = (const float*)d_in[4];
  const float* Wk = (const float*)d_in[5];  const float* bk = (const float*)d_in[6];
  const float* Wv = (const float*)d_in[7];  const float* bv = (const float*)d_in[8];
  const float* wld = (const float*)d_in[9];  const float* bld = (const float*)d_in[10];
  const float* wl1 = (const float*)d_in[11]; const float* bl1 = (const float*)d_in[12];
  const float* wad = (const float*)d_in[13]; const float* bad = (const float*)d_in[14];
  const float* wa1 = (const float*)d_in[15]; const float* ba1 = (const float*)d_in[16];
  const float* Wa2 = (const float*)d_in[17]; const float* ba2 = (const float*)d_in[18];
  const float* wtd = (const float*)d_in[19]; const float* btd = (const float*)d_in[20];
  const float* wt1 = (const float*)d_in[21]; const float* bt1 = (const float*)d_in[22];
  const float* Wt2 = (const float*)d_in[23]; const float* bt2 = (const float*)d_in[24];
  float* ws = (float*)d_ws;
  float* fout = (float*)d_out;

  hipMemsetAsync((void*)(ws + OFF_SUM), 0, 3 * nB * nL * sizeof(float), stream);
  k_vecs<<<13, 64, 0, stream>>>(Wq, Wk, Wv, bq, bk, bv, wld, wad, wtd, ws);
  // MT[d1][d] = sum_j Wq[d1,j] Wk[d,j]
  mm_nt<<<dim3(12, 12, 1), 256, 0, stream>>>(Wq, Wk, ws + OFF_MT, nullptr,
                                             nD, nD, nD, 0, 0);
  // kqT[b][d1][s] = sum_d MT[d1,d] * out[b,s,d] + qbk[d1]
  mm_nt<<<dim3(8, 12, nB), 256, 0, stream>>>(ws + OFF_MT, outp, ws + OFF_KQT,
                                             ws + OFF_QBK, nD, nS, nD,
                                             (long)nS * nD, (long)nD * nS);
  // pack kqT -> bf16 B-fragments (overwrites MT region; MT no longer needed)
  k_pack<<<dim3(4, 96), 256, 0, stream>>>(ws + OFF_KQT, (unsigned short*)(ws + OFF_KQB));
  k_chv<<<nB * nS, 64, 0, stream>>>(outp, ws);
  k_attn<<<dim3(nR / 32, nB, nL), 256, 0, stream>>>(laws, (const unsigned short*)(ws + OFF_KQB),
                                                    mask, ws, bld, wl1, bad, wa1, btd, wt1);
  k_final<<<1, 256, 0, stream>>>(ws, fout, bl1, ba1, Wa2, ba2, bt1, Wt2, bt2);
}

// Round 3
// 586.460 us; speedup vs baseline: 3.0373x; 1.0787x over previous
//
#include <hip/hip_runtime.h>

static constexpr int nL = 103, nR = 512, nB = 2, nS = 512, nD = 768;
static constexpr float INV_SQRT_D = 0.03608439182435161f; // 1/sqrt(768)

typedef short bf16x8 __attribute__((ext_vector_type(8)));
typedef float f32x4 __attribute__((ext_vector_type(4)));
typedef unsigned short ushort4v __attribute__((ext_vector_type(4)));
typedef unsigned short ushort8v __attribute__((ext_vector_type(8)));

// ws layout (float offsets)
static constexpr size_t OFF_MT   = 0;                         // 768*768 fp32
static constexpr size_t OFF_KQB  = (size_t)nD * nD;           // 96*1024*8 ushorts = 393216 floats
static constexpr size_t OFF_QBK  = OFF_KQB + 393216;          // nD : Wq@bk
static constexpr size_t OFF_WKBQ = OFF_QBK + nD;              // nD : Wk@bq
static constexpr size_t OFF_WV3  = OFF_WKBQ + nD;             // 3*nD : Wv@{wld,wad,wtd}
static constexpr size_t OFF_CST  = OFF_WV3 + 3 * (size_t)nD;  // 4
static constexpr size_t OFF_C    = OFF_CST + 4;               // nB*nS
static constexpr size_t OFF_HV   = OFF_C + (size_t)nB * nS;   // 3*nB*nS
static constexpr size_t OFF_SUM  = OFF_HV + 3 * (size_t)nB * nS; // 3*nB*nL

__device__ inline float wredsum(float v) {
#pragma unroll
  for (int o = 32; o; o >>= 1) v += __shfl_xor(v, o);
  return v;
}

__device__ inline unsigned short f2bf(float f) {  // RNE fp32 -> bf16
  unsigned u = __builtin_bit_cast(unsigned, f);
  u += 0x7FFFu + ((u >> 16) & 1u);
  return (unsigned short)(u >> 16);
}

// ---- K0: small matvecs + consts + zero-init (MT, SUM) ----------------------
__global__ void k_vecs(const float* __restrict__ Wq, const float* __restrict__ Wk,
                       const float* __restrict__ Wv, const float* __restrict__ bq,
                       const float* __restrict__ bk, const float* __restrict__ bv,
                       const float* __restrict__ wld, const float* __restrict__ wad,
                       const float* __restrict__ wtd, float* __restrict__ ws) {
  int lane = threadIdx.x;
  if (blockIdx.x < 12) {
    int d = blockIdx.x * 64 + lane;
    const float* wqr = Wq + (size_t)d * nD;
    const float* wkr = Wk + (size_t)d * nD;
    const float* wvr = Wv + (size_t)d * nD;
    float q = 0.f, k = 0.f, a0 = 0.f, a1 = 0.f, a2 = 0.f;
    for (int j = 0; j < nD; j += 4) {
      float4 q4 = *(const float4*)(wqr + j);
      float4 k4 = *(const float4*)(wkr + j);
      float4 v4 = *(const float4*)(wvr + j);
      float4 bk4 = *(const float4*)(bk + j);
      float4 bq4 = *(const float4*)(bq + j);
      float4 l4 = *(const float4*)(wld + j);
      float4 a4 = *(const float4*)(wad + j);
      float4 t4 = *(const float4*)(wtd + j);
      q  += q4.x*bk4.x + q4.y*bk4.y + q4.z*bk4.z + q4.w*bk4.w;
      k  += k4.x*bq4.x + k4.y*bq4.y + k4.z*bq4.z + k4.w*bq4.w;
      a0 += v4.x*l4.x + v4.y*l4.y + v4.z*l4.z + v4.w*l4.w;
      a1 += v4.x*a4.x + v4.y*a4.y + v4.z*a4.z + v4.w*a4.w;
      a2 += v4.x*t4.x + v4.y*t4.y + v4.z*t4.z + v4.w*t4.w;
    }
    ws[OFF_QBK + d]  = q;
    ws[OFF_WKBQ + d] = k;
    ws[OFF_WV3 + d]        = a0;
    ws[OFF_WV3 + nD + d]   = a1;
    ws[OFF_WV3 + 2*nD + d] = a2;
  } else if (blockIdx.x == 12) {
    float c0 = 0.f, c1 = 0.f, c2 = 0.f, c3 = 0.f;
    for (int j = lane; j < nD; j += 64) {
      c0 += bq[j]*bk[j]; c1 += bv[j]*wld[j]; c2 += bv[j]*wad[j]; c3 += bv[j]*wtd[j];
    }
    c0 = wredsum(c0); c1 = wredsum(c1); c2 = wredsum(c2); c3 = wredsum(c3);
    if (lane == 0) {
      ws[OFF_CST+0] = c0; ws[OFF_CST+1] = c1; ws[OFF_CST+2] = c2; ws[OFF_CST+3] = c3;
    }
    for (int i = lane; i < 3 * nB * nL; i += 64) ws[OFF_SUM + i] = 0.f;
  } else {
    // zero MT: blocks 13..44, 18432 floats each (32 blocks * 18432 = 589824)
    float* base = ws + OFF_MT + (size_t)(blockIdx.x - 13) * 18432;
    float4 z = {0.f, 0.f, 0.f, 0.f};
    for (int i = lane; i < 4608; i += 64) *(float4*)(base + (size_t)i * 4) = z;
  }
}

// ---- MT GEMM, split-K4 + atomicAdd: MT[m,n] = sum_k Wq[m,k]Wk[n,k] ---------
__global__ __launch_bounds__(256) void mm_nt_at(const float* __restrict__ A,
                                                const float* __restrict__ Bm,
                                                float* __restrict__ C,
                                                int M, int N, int K) {
  __shared__ float Ast[16][68];
  __shared__ float Bst[16][68];
  int m0 = blockIdx.y * 64, n0 = blockIdx.x * 64;
  int kz = blockIdx.z;
  int tid = threadIdx.x;
  int tx = tid & 15, ty = tid >> 4;
  int li = (tid * 4) >> 4;
  int lj = (tid * 4) & 15;
  float acc[4][4] = {};
  for (int k0 = kz * 192; k0 < kz * 192 + 192; k0 += 16) {
    float4 a4 = *(const float4*)(A  + (size_t)(m0 + li) * K + k0 + lj);
    float4 b4 = *(const float4*)(Bm + (size_t)(n0 + li) * K + k0 + lj);
    __syncthreads();
    Ast[lj+0][li] = a4.x; Ast[lj+1][li] = a4.y; Ast[lj+2][li] = a4.z; Ast[lj+3][li] = a4.w;
    Bst[lj+0][li] = b4.x; Bst[lj+1][li] = b4.y; Bst[lj+2][li] = b4.z; Bst[lj+3][li] = b4.w;
    __syncthreads();
#pragma unroll
    for (int kk = 0; kk < 16; ++kk) {
      float4 av4 = *(const float4*)&Ast[kk][ty * 4];
      float4 bv4 = *(const float4*)&Bst[kk][tx * 4];
      float av[4] = {av4.x, av4.y, av4.z, av4.w};
      float bv[4] = {bv4.x, bv4.y, bv4.z, bv4.w};
#pragma unroll
      for (int mi = 0; mi < 4; ++mi)
#pragma unroll
        for (int ni = 0; ni < 4; ++ni) acc[mi][ni] += av[mi] * bv[ni];
    }
  }
#pragma unroll
  for (int mi = 0; mi < 4; ++mi) {
    int m = m0 + ty * 4 + mi;
#pragma unroll
    for (int ni = 0; ni < 4; ++ni)
      atomicAdd(&C[(size_t)m * N + n0 + tx * 4 + ni], acc[mi][ni]);
  }
}

// ---- kq GEMM (s-major) + fused bf16 pack: C[s][d1]=out[b,s,:].MT[d1,:]+qbk -
__global__ __launch_bounds__(256) void mm_pack(const float* __restrict__ outp,
                                               const float* __restrict__ MT,
                                               const float* __restrict__ qbk,
                                               unsigned short* __restrict__ kqB) {
  __shared__ float Ast[16][68];
  __shared__ float Bst[16][68];
  int b = blockIdx.z;
  const float* Ap = outp + (size_t)b * nS * nD;
  int m0 = blockIdx.y * 64, n0 = blockIdx.x * 64;
  int tid = threadIdx.x;
  int tx = tid & 15, ty = tid >> 4;
  int li = (tid * 4) >> 4;
  int lj = (tid * 4) & 15;
  float acc[4][4] = {};
  for (int k0 = 0; k0 < nD; k0 += 16) {
    float4 a4 = *(const float4*)(Ap + (size_t)(m0 + li) * nD + k0 + lj);
    float4 b4 = *(const float4*)(MT + (size_t)(n0 + li) * nD + k0 + lj);
    __syncthreads();
    Ast[lj+0][li] = a4.x; Ast[lj+1][li] = a4.y; Ast[lj+2][li] = a4.z; Ast[lj+3][li] = a4.w;
    Bst[lj+0][li] = b4.x; Bst[lj+1][li] = b4.y; Bst[lj+2][li] = b4.z; Bst[lj+3][li] = b4.w;
    __syncthreads();
#pragma unroll
    for (int kk = 0; kk < 16; ++kk) {
      float4 av4 = *(const float4*)&Ast[kk][ty * 4];
      float4 bv4 = *(const float4*)&Bst[kk][tx * 4];
      float av[4] = {av4.x, av4.y, av4.z, av4.w};
      float bv[4] = {bv4.x, bv4.y, bv4.z, bv4.w};
#pragma unroll
      for (int mi = 0; mi < 4; ++mi)
#pragma unroll
        for (int ni = 0; ni < 4; ++ni) acc[mi][ni] += av[mi] * bv[ni];
    }
  }
  int nbase = n0 + tx * 4;
  int g = nbase >> 3, j0 = nbase & 7;  // j0 in {0,4}
  float q0 = qbk[nbase], q1 = qbk[nbase+1], q2 = qbk[nbase+2], q3 = qbk[nbase+3];
#pragma unroll
  for (int mi = 0; mi < 4; ++mi) {
    int m = m0 + ty * 4 + mi;
    ushort4v o;
    o[0] = f2bf(acc[mi][0] + q0);
    o[1] = f2bf(acc[mi][1] + q1);
    o[2] = f2bf(acc[mi][2] + q2);
    o[3] = f2bf(acc[mi][3] + q3);
    *(ushort4v*)(kqB + ((size_t)g * 1024 + (size_t)b * nS + m) * 8 + j0) = o;
  }
}

// ---- K2: per-(b,s) scalars c, hv_law/accu/term -----------------------------
__global__ void k_chv(const float* __restrict__ outp, float* __restrict__ ws) {
  int bs = blockIdx.x;
  int lane = threadIdx.x;
  const float* row = outp + (size_t)bs * nD;
  const float* wkbq = ws + OFF_WKBQ;
  const float* wv0 = ws + OFF_WV3;
  const float* wv1 = ws + OFF_WV3 + nD;
  const float* wv2 = ws + OFF_WV3 + 2*nD;
  float a0 = 0.f, a1 = 0.f, a2 = 0.f, a3 = 0.f;
  for (int d = lane * 4; d < nD; d += 256) {
    float4 o4 = *(const float4*)(row + d);
    float4 k4 = *(const float4*)(wkbq + d);
    float4 l4 = *(const float4*)(wv0 + d);
    float4 c4 = *(const float4*)(wv1 + d);
    float4 t4 = *(const float4*)(wv2 + d);
    a0 += o4.x*k4.x + o4.y*k4.y + o4.z*k4.z + o4.w*k4.w;
    a1 += o4.x*l4.x + o4.y*l4.y + o4.z*l4.z + o4.w*l4.w;
    a2 += o4.x*c4.x + o4.y*c4.y + o4.z*c4.z + o4.w*c4.w;
    a3 += o4.x*t4.x + o4.y*t4.y + o4.z*t4.z + o4.w*t4.w;
  }
  a0 = wredsum(a0); a1 = wredsum(a1); a2 = wredsum(a2); a3 = wredsum(a3);
  if (lane == 0) {
    ws[OFF_C + bs]             = a0 + ws[OFF_CST+0];
    ws[OFF_HV + bs]            = a1 + ws[OFF_CST+1];
    ws[OFF_HV + nB*nS + bs]    = a2 + ws[OFF_CST+2];
    ws[OFF_HV + 2*nB*nS + bs]  = a3 + ws[OFF_CST+3];
  }
}

// ---- K3: 128x512 MFMA tile, dbuf LDS A, reg-prefetched B, fused softmax ----
// block = (r-tile of 128, b, l); 8 waves: wr=w>>2 (r-half), wc=w&3 (s-quarter)
__global__ __launch_bounds__(512, 2) void k_attn(
    const float* __restrict__ laws, const unsigned short* __restrict__ kqB,
    const int* __restrict__ mask, float* __restrict__ ws,
    const float* __restrict__ bld, const float* __restrict__ wl1,
    const float* __restrict__ bad, const float* __restrict__ wa1,
    const float* __restrict__ btd, const float* __restrict__ wt1) {
  __shared__ unsigned short Abuf[2][128 * 40];     // bf16 A k-slice, dbuf, 20 KB
  __shared__ float redS[4][128][4][4];             // [wc][row][grp][stat], 32 KB
  const int tid = threadIdx.x;
  const int lane = tid & 63, w = tid >> 6;
  const int c4 = lane & 15, q4 = lane >> 4;
  const int wc = w & 3, wr = w >> 2;
  const int bx = blockIdx.x, b = blockIdx.y, l = blockIdx.z;

  // ---- A staging: thread -> (row srow, 8-wide quad sq) ----------------------
  const int srow = tid >> 2, sq = tid & 3;
  const float* Asrc = laws + ((size_t)l * nR + (size_t)bx * 128 + srow) * nD + sq * 8;
  unsigned short* Aw = &Abuf[0][srow * 40 + sq * 8];

  {  // stage kt=0
    float4 f0 = *(const float4*)(Asrc);
    float4 f1 = *(const float4*)(Asrc + 4);
    ushort8v u;
    u[0]=f2bf(f0.x); u[1]=f2bf(f0.y); u[2]=f2bf(f0.z); u[3]=f2bf(f0.w);
    u[4]=f2bf(f1.x); u[5]=f2bf(f1.y); u[6]=f2bf(f1.z); u[7]=f2bf(f1.w);
    *(ushort8v*)Aw = u;
  }

  // ---- B prefetch base: frag lane(c4,q4), col s = wc*128 + ct*16 + c4 ------
  const unsigned short* Bbase =
      kqB + ((size_t)q4 * 1024 + (size_t)b * nS + wc * 128 + c4) * 8;
  bf16x8 Bc[8];
#pragma unroll
  for (int t = 0; t < 8; ++t) Bc[t] = *(const bf16x8*)(Bbase + t * 128);
  __syncthreads();

  f32x4 acc[4][8];
#pragma unroll
  for (int rt = 0; rt < 4; ++rt)
#pragma unroll
    for (int ct = 0; ct < 8; ++ct) acc[rt][ct] = (f32x4){0.f, 0.f, 0.f, 0.f};

  // ---- K loop: 24 slices of 32 --------------------------------------------
  for (int kt = 0; kt < 24; ++kt) {
    int nxt = kt + 1;
    float4 f0n, f1n;
    bf16x8 Bn[8];
    if (nxt < 24) {
      f0n = *(const float4*)(Asrc + nxt * 32);
      f1n = *(const float4*)(Asrc + nxt * 32 + 4);
#pragma unroll
      for (int t = 0; t < 8; ++t)
        Bn[t] = *(const bf16x8*)(Bbase + (size_t)nxt * 32768 + t * 128);
    }
    const unsigned short* Ab = &Abuf[kt & 1][0];
    bf16x8 af[4];
#pragma unroll
    for (int rt = 0; rt < 4; ++rt)
      af[rt] = *(const bf16x8*)&Ab[(wr * 64 + rt * 16 + c4) * 40 + q4 * 8];
#pragma unroll
    for (int rt = 0; rt < 4; ++rt)
#pragma unroll
      for (int ct = 0; ct < 8; ++ct)
        acc[rt][ct] = __builtin_amdgcn_mfma_f32_16x16x32_bf16(af[rt], Bc[ct],
                                                              acc[rt][ct], 0, 0, 0);
    if (nxt < 24) {
      ushort8v u;
      u[0]=f2bf(f0n.x); u[1]=f2bf(f0n.y); u[2]=f2bf(f0n.z); u[3]=f2bf(f0n.w);
      u[4]=f2bf(f1n.x); u[5]=f2bf(f1n.y); u[6]=f2bf(f1n.z); u[7]=f2bf(f1n.w);
      *(ushort8v*)(Aw + (nxt & 1) * (128 * 40)) = u;
#pragma unroll
      for (int t = 0; t < 8; ++t) Bc[t] = Bn[t];
    }
    __syncthreads();
  }

  // ---- per-col scalars: s = wc*128 + ct*16 + c4 ----------------------------
  const float* cp  = ws + OFF_C + (size_t)b * nS;
  const float* hlp = ws + OFF_HV + (size_t)b * nS;
  const float* hap = ws + OFF_HV + (size_t)nB * nS + (size_t)b * nS;
  const float* htp = ws + OFF_HV + 2 * (size_t)nB * nS + (size_t)b * nS;
  float cc[8], hl[8], ha[8], ht[8], ma[8];
#pragma unroll
  for (int ct = 0; ct < 8; ++ct) {
    int s = wc * 128 + ct * 16 + c4;
    cc[ct] = cp[s]; hl[ct] = hlp[s]; ha[ct] = hap[s]; ht[ct] = htp[s];
    ma[ct] = (1.0f - (float)mask[b * nS + s]) * -10000.0f;
  }

  // ---- exp (no max: logits bounded, masked -> underflow 0) + 4 row sums ----
  float se[4][4] = {}, pl[4][4] = {}, pa[4][4] = {}, pt[4][4] = {};
#pragma unroll
  for (int rt = 0; rt < 4; ++rt)
#pragma unroll
    for (int ct = 0; ct < 8; ++ct) {
      f32x4 v = acc[rt][ct];
#pragma unroll
      for (int reg = 0; reg < 4; ++reg) {
        float x = (v[reg] + cc[ct]) * INV_SQRT_D + ma[ct];
        float e = __expf(x);
        se[rt][reg] += e;
        pl[rt][reg] += e * hl[ct];
        pa[rt][reg] += e * ha[ct];
        pt[rt][reg] += e * ht[ct];
      }
    }
  // 2 xor steps over c4 -> 4 partials per row (grp = c4>>2)
#pragma unroll
  for (int rt = 0; rt < 4; ++rt)
#pragma unroll
    for (int reg = 0; reg < 4; ++reg) {
      se[rt][reg] += __shfl_xor(se[rt][reg], 1);
      pl[rt][reg] += __shfl_xor(pl[rt][reg], 1);
      pa[rt][reg] += __shfl_xor(pa[rt][reg], 1);
      pt[rt][reg] += __shfl_xor(pt[rt][reg], 1);
      se[rt][reg] += __shfl_xor(se[rt][reg], 2);
      pl[rt][reg] += __shfl_xor(pl[rt][reg], 2);
      pa[rt][reg] += __shfl_xor(pa[rt][reg], 2);
      pt[rt][reg] += __shfl_xor(pt[rt][reg], 2);
    }
  if ((c4 & 3) == 0) {
    int grp = c4 >> 2;
#pragma unroll
    for (int rt = 0; rt < 4; ++rt)
#pragma unroll
      for (int reg = 0; reg < 4; ++reg) {
        int row = wr * 64 + rt * 16 + q4 * 4 + reg;
        f32x4 st = {se[rt][reg], pl[rt][reg], pa[rt][reg], pt[rt][reg]};
        *(f32x4*)&redS[wc][row][grp][0] = st;
      }
  }
  __syncthreads();

  // ---- finalize on waves 0,1: one row per lane -----------------------------
  if (w < 2) {
    int row = w * 64 + lane;
    f32x4 t = (f32x4){0.f, 0.f, 0.f, 0.f};
#pragma unroll
    for (int wci = 0; wci < 4; ++wci)
#pragma unroll
      for (int g = 0; g < 4; ++g) t += *(const f32x4*)&redS[wci][row][g][0];
    float inv = 1.0f / t[0];
    int r = bx * 128 + row;
    float cl = tanhf(t[1] * inv + bld[0]) * wl1[r];
    float ca = tanhf(t[2] * inv + bad[0]) * wa1[r];
    float ctv = tanhf(t[3] * inv + btd[0]) * wt1[r];
#pragma unroll
    for (int o = 1; o < 64; o <<= 1) {
      cl += __shfl_xor(cl, o);
      ca += __shfl_xor(ca, o);
      ctv += __shfl_xor(ctv, o);
    }
    if (lane == 0) {
      float* sums = ws + OFF_SUM;
      atomicAdd(&sums[b * nL + l], cl);
      atomicAdd(&sums[nB * nL + b * nL + l], ca);
      atomicAdd(&sums[2 * nB * nL + b * nL + l], ctv);
    }
  }
}

// ---- K4: finalize heads ----------------------------------------------------
__global__ void k_final(const float* __restrict__ ws, float* __restrict__ out,
                        const float* __restrict__ bl1, const float* __restrict__ ba1,
                        const float* __restrict__ Wa2, const float* __restrict__ ba2,
                        const float* __restrict__ bt1, const float* __restrict__ Wt2,
                        const float* __restrict__ bt2) {
  __shared__ float abl[nB * nL], tbl[nB * nL];
  int t = threadIdx.x;
  const float* sl = ws + OFF_SUM;
  const float* sa = sl + nB * nL;
  const float* st = sa + nB * nL;
  if (t < nB * nL) {
    out[t] = sl[t] + bl1[0];
    abl[t] = tanhf(sa[t] + ba1[0]);
    tbl[t] = tanhf(st[t] + bt1[0]);
  }
  __syncthreads();
  for (int idx = t; idx < nB * 119; idx += 256) {
    int b = idx / 119, j = idx % 119;
    float a = ba2[j];
    for (int ll = 0; ll < nL; ++ll) a += Wa2[j * nL + ll] * abl[b * nL + ll];
    out[nB * nL + idx] = a;
  }
  for (int idx = t; idx < nB * 11; idx += 256) {
    int b = idx / 11, j = idx % 11;
    float a = bt2[j];
    for (int ll = 0; ll < nL; ++ll) a += Wt2[j * nL + ll] * tbl[b * nL + ll];
    out[nB * nL + nB * 119 + idx] = a;
  }
}

extern "C" void kernel_launch(void* const* d_in, const int* in_sizes, int n_in,
                              void* d_out, int out_size, void* d_ws, size_t ws_size,
                              hipStream_t stream) {
  (void)in_sizes; (void)n_in; (void)out_size; (void)ws_size;
  const float* outp = (const float*)d_in[0];
  const int*   mask = (const int*)d_in[1];
  const float* laws = (const float*)d_in[2];
  const float* Wq = (const float*)d_in[3];  const float* bq = (const float*)d_in[4];
  const float* Wk = (const float*)d_in[5];  const float* bk = (const float*)d_in[6];
  const float* Wv = (const float*)d_in[7];  const float* bv = (const float*)d_in[8];
  const float* wld = (const float*)d_in[9];  const float* bld = (const float*)d_in[10];
  const float* wl1 = (const float*)d_in[11]; const float* bl1 = (const float*)d_in[12];
  const float* wad = (const float*)d_in[13]; const float* bad = (const float*)d_in[14];
  const float* wa1 = (const float*)d_in[15]; const float* ba1 = (const float*)d_in[16];
  const float* Wa2 = (const float*)d_in[17]; const float* ba2 = (const float*)d_in[18];
  const float* wtd = (const float*)d_in[19]; const float* btd = (const float*)d_in[20];
  const float* wt1 = (const float*)d_in[21]; const float* bt1 = (const float*)d_in[22];
  const float* Wt2 = (const float*)d_in[23]; const float* bt2 = (const float*)d_in[24];
  float* ws = (float*)d_ws;
  float* fout = (float*)d_out;
  unsigned short* kqB = (unsigned short*)(ws + OFF_KQB);

  // 1) matvecs + consts + zero MT/SUM
  k_vecs<<<45, 64, 0, stream>>>(Wq, Wk, Wv, bq, bk, bv, wld, wad, wtd, ws);
  // 2) MT[d1][d] = sum_j Wq[d1,j] Wk[d,j]  (split-K4, atomic)
  mm_nt_at<<<dim3(12, 12, 4), 256, 0, stream>>>(Wq, Wk, ws + OFF_MT, nD, nD, nD);
  // 3) kq s-major + pack: kqB[g][b*512+s][j] = bf16(out[b,s,:].MT[g*8+j,:] + qbk)
  mm_pack<<<dim3(12, 8, nB), 256, 0, stream>>>(outp, ws + OFF_MT, ws + OFF_QBK, kqB);
  // 4) per-(b,s) scalars
  k_chv<<<nB * nS, 64, 0, stream>>>(outp, ws);
  // 5) fused scores+softmax+heads
  k_attn<<<dim3(4, nB, nL), 512, 0, stream>>>(laws, kqB, mask, ws,
                                              bld, wl1, bad, wa1, btd, wt1);
  // 6) output heads
  k_final<<<1, 256, 0, stream>>>(ws, fout, bl1, ba1, Wa2, ba2, bt1, Wt2, bt2);
}

// Round 5
// 513.781 us; speedup vs baseline: 3.4669x; 1.1415x over previous
//
#include <hip/hip_runtime.h>

static constexpr int nL = 103, nR = 512, nB = 2, nS = 512, nD = 768;
static constexpr float INV_SQRT_D = 0.03608439182435161f; // 1/sqrt(768)

typedef short bf16x8 __attribute__((ext_vector_type(8)));
typedef float f32x4 __attribute__((ext_vector_type(4)));
typedef unsigned short u16;
typedef unsigned short ushort4v __attribute__((ext_vector_type(4)));
typedef unsigned short ushort8v __attribute__((ext_vector_type(8)));

// ws layout (float offsets). Total 1,286,510 fl = 4.91 MiB (<= 5.28 MiB proven).
// kqB aliases wqb+wkb: those are dead once mm_bf step 3 has consumed them.
static constexpr size_t OFF_WQB  = 0;                  // 294912 fl (bf16 768x768)
static constexpr size_t OFF_WKB  = 294912;             // 294912 fl
static constexpr size_t OFF_KQB  = 0;                  // 393216 fl, written by mm_bf step 4
static constexpr size_t OFF_OUTB = 589824;             // 393216 fl (bf16 1024x768)
static constexpr size_t OFF_MBF  = 983040;             // 294912 fl (bf16 M = Wq@Wk^T)
static constexpr size_t OFF_QBK  = 1277952;            // 768 : Wq@bk
static constexpr size_t OFF_WKBQ = OFF_QBK + 768;      // 768 : Wk@bq
static constexpr size_t OFF_WV3  = OFF_WKBQ + 768;     // 3*768 : Wv@{wld,wad,wtd}
static constexpr size_t OFF_CST  = OFF_WV3 + 2304;     // 4
static constexpr size_t OFF_C    = OFF_CST + 4;        // 1024
static constexpr size_t OFF_HV   = OFF_C + 1024;       // 3*1024
static constexpr size_t OFF_SUM  = OFF_HV + 3072;      // 3*nB*nL = 618

__device__ inline float wredsum(float v) {
#pragma unroll
  for (int o = 32; o; o >>= 1) v += __shfl_xor(v, o);
  return v;
}

__device__ inline u16 f2bf(float f) {  // RNE fp32 -> bf16
  unsigned u = __builtin_bit_cast(unsigned, f);
  u += 0x7FFFu + ((u >> 16) & 1u);
  return (u16)(u >> 16);
}

// ---- K0: coalesced row-dots (wave per row) + consts + zero SUM -------------
__global__ __launch_bounds__(256) void k_prep(
    const float* __restrict__ Wq, const float* __restrict__ Wk,
    const float* __restrict__ Wv, const float* __restrict__ bq,
    const float* __restrict__ bk, const float* __restrict__ bv,
    const float* __restrict__ wld, const float* __restrict__ wad,
    const float* __restrict__ wtd, float* __restrict__ ws) {
  int tid = threadIdx.x, lane = tid & 63, w = tid >> 6;
  if (blockIdx.x < 192) {
    int row = blockIdx.x * 4 + w;
    const float* wqr = Wq + (size_t)row * nD;
    const float* wkr = Wk + (size_t)row * nD;
    const float* wvr = Wv + (size_t)row * nD;
    float dq = 0.f, dk = 0.f, d0 = 0.f, d1 = 0.f, d2 = 0.f;
#pragma unroll
    for (int k = 0; k < 3; ++k) {
      int off = lane * 4 + k * 256;
      float4 q4 = *(const float4*)(wqr + off);
      float4 k4 = *(const float4*)(wkr + off);
      float4 v4 = *(const float4*)(wvr + off);
      float4 bk4 = *(const float4*)(bk + off);
      float4 bq4 = *(const float4*)(bq + off);
      float4 l4 = *(const float4*)(wld + off);
      float4 a4 = *(const float4*)(wad + off);
      float4 t4 = *(const float4*)(wtd + off);
      dq += q4.x*bk4.x + q4.y*bk4.y + q4.z*bk4.z + q4.w*bk4.w;
      dk += k4.x*bq4.x + k4.y*bq4.y + k4.z*bq4.z + k4.w*bq4.w;
      d0 += v4.x*l4.x + v4.y*l4.y + v4.z*l4.z + v4.w*l4.w;
      d1 += v4.x*a4.x + v4.y*a4.y + v4.z*a4.z + v4.w*a4.w;
      d2 += v4.x*t4.x + v4.y*t4.y + v4.z*t4.z + v4.w*t4.w;
    }
    dq = wredsum(dq); dk = wredsum(dk);
    d0 = wredsum(d0); d1 = wredsum(d1); d2 = wredsum(d2);
    if (lane == 0) {
      ws[OFF_QBK + row] = dq;
      ws[OFF_WKBQ + row] = dk;
      ws[OFF_WV3 + row] = d0;
      ws[OFF_WV3 + 768 + row] = d1;
      ws[OFF_WV3 + 1536 + row] = d2;
    }
  } else {
    if (tid < 64) {
      float c0 = 0.f, c1 = 0.f, c2 = 0.f, c3 = 0.f;
      for (int j = lane; j < nD; j += 64) {
        c0 += bq[j]*bk[j]; c1 += bv[j]*wld[j]; c2 += bv[j]*wad[j]; c3 += bv[j]*wtd[j];
      }
      c0 = wredsum(c0); c1 = wredsum(c1); c2 = wredsum(c2); c3 = wredsum(c3);
      if (lane == 0) {
        ws[OFF_CST+0] = c0; ws[OFF_CST+1] = c1; ws[OFF_CST+2] = c2; ws[OFF_CST+3] = c3;
      }
    }
    for (int i = tid; i < 3 * nB * nL; i += 256) ws[OFF_SUM + i] = 0.f;
  }
}

// ---- K1: pack Wq, Wk, out -> bf16 row-major --------------------------------
__global__ __launch_bounds__(256) void k_pack(const float* __restrict__ Wq,
                                              const float* __restrict__ Wk,
                                              const float* __restrict__ outp,
                                              u16* __restrict__ wqb,
                                              u16* __restrict__ wkb,
                                              u16* __restrict__ outb) {
  int bid = blockIdx.x;
  const float* src; u16* dst; int base;
  if (bid < 144)      { src = Wq;   dst = wqb;  base = bid; }
  else if (bid < 288) { src = Wk;   dst = wkb;  base = bid - 144; }
  else                { src = outp; dst = outb; base = bid - 288; }
  size_t e = ((size_t)base * 256 + threadIdx.x) * 16;
  float4 f0 = *(const float4*)(src + e);
  float4 f1 = *(const float4*)(src + e + 4);
  float4 f2 = *(const float4*)(src + e + 8);
  float4 f3 = *(const float4*)(src + e + 12);
  ushort8v u0, u1;
  u0[0]=f2bf(f0.x); u0[1]=f2bf(f0.y); u0[2]=f2bf(f0.z); u0[3]=f2bf(f0.w);
  u0[4]=f2bf(f1.x); u0[5]=f2bf(f1.y); u0[6]=f2bf(f1.z); u0[7]=f2bf(f1.w);
  u1[0]=f2bf(f2.x); u1[1]=f2bf(f2.y); u1[2]=f2bf(f2.z); u1[3]=f2bf(f2.w);
  u1[4]=f2bf(f3.x); u1[5]=f2bf(f3.y); u1[6]=f2bf(f3.z); u1[7]=f2bf(f3.w);
  *(ushort8v*)(dst + e) = u0;
  *(ushort8v*)(dst + e + 8) = u1;
}

// ---- MFMA NT GEMM (bf16, K=768): C[m,n] = sum_k A[m,k]B[n,k] ---------------
// 128x128 tile, 8 waves (wr 2 x wc 4), wave 64x32.
// mode 0: C = bf16 row-major stride 768.  mode 1: C -> kqB frag layout + bias.
__global__ __launch_bounds__(512) void mm_bf(const u16* __restrict__ A,
                                             const u16* __restrict__ B,
                                             u16* __restrict__ C,
                                             const float* __restrict__ bias,
                                             int mode) {
  __shared__ u16 Ast[128 * 40];
  __shared__ u16 Bst[128 * 40];
  const int tid = threadIdx.x, lane = tid & 63, w = tid >> 6;
  const int c4 = lane & 15, q4 = lane >> 4, wr = w >> 2, wc = w & 3;
  const int m0 = blockIdx.y * 128, n0 = blockIdx.x * 128;
  const int sr = tid >> 2, seg = tid & 3;
  const u16* Asrc = A + (size_t)(m0 + sr) * 768 + seg * 8;
  const u16* Bsrc = B + (size_t)(n0 + sr) * 768 + seg * 8;
  f32x4 acc[4][2];
#pragma unroll
  for (int rt = 0; rt < 4; ++rt)
#pragma unroll
    for (int ct = 0; ct < 2; ++ct) acc[rt][ct] = (f32x4){0.f,0.f,0.f,0.f};
  for (int kt = 0; kt < 24; ++kt) {
    ushort8v av = *(const ushort8v*)(Asrc + kt * 32);
    ushort8v bv = *(const ushort8v*)(Bsrc + kt * 32);
    __syncthreads();
    *(ushort8v*)&Ast[sr * 40 + seg * 8] = av;
    *(ushort8v*)&Bst[sr * 40 + seg * 8] = bv;
    __syncthreads();
    bf16x8 af[4], bf[2];
#pragma unroll
    for (int rt = 0; rt < 4; ++rt)
      af[rt] = *(const bf16x8*)&Ast[(wr * 64 + rt * 16 + c4) * 40 + q4 * 8];
#pragma unroll
    for (int ct = 0; ct < 2; ++ct)
      bf[ct] = *(const bf16x8*)&Bst[(wc * 32 + ct * 16 + c4) * 40 + q4 * 8];
#pragma unroll
    for (int rt = 0; rt < 4; ++rt)
#pragma unroll
      for (int ct = 0; ct < 2; ++ct)
        acc[rt][ct] = __builtin_amdgcn_mfma_f32_16x16x32_bf16(af[rt], bf[ct],
                                                              acc[rt][ct], 0, 0, 0);
  }
#pragma unroll
  for (int rt = 0; rt < 4; ++rt)
#pragma unroll
    for (int ct = 0; ct < 2; ++ct) {
      int n = n0 + wc * 32 + ct * 16 + c4;
      float bb = (mode == 1) ? bias[n] : 0.0f;
#pragma unroll
      for (int reg = 0; reg < 4; ++reg) {
        int m = m0 + wr * 64 + rt * 16 + q4 * 4 + reg;
        float v = acc[rt][ct][reg] + bb;
        if (mode == 0) C[(size_t)m * 768 + n] = f2bf(v);
        else C[(((size_t)(n >> 3)) << 13) + ((size_t)m << 3) + (n & 7)] = f2bf(v);
      }
    }
}

// ---- K2: per-(b,s) scalars c, hv (wave per row) ----------------------------
__global__ __launch_bounds__(256) void k_chv(const float* __restrict__ outp,
                                             float* __restrict__ ws) {
  int tid = threadIdx.x, lane = tid & 63, w = tid >> 6;
  int idx = blockIdx.x * 4 + w;
  const float* row = outp + (size_t)idx * nD;
  const float* wkbq = ws + OFF_WKBQ;
  const float* wv0 = ws + OFF_WV3;
  const float* wv1 = ws + OFF_WV3 + 768;
  const float* wv2 = ws + OFF_WV3 + 1536;
  float a0 = 0.f, a1 = 0.f, a2 = 0.f, a3 = 0.f;
#pragma unroll
  for (int k = 0; k < 3; ++k) {
    int off = lane * 4 + k * 256;
    float4 o4 = *(const float4*)(row + off);
    float4 k4 = *(const float4*)(wkbq + off);
    float4 l4 = *(const float4*)(wv0 + off);
    float4 c4 = *(const float4*)(wv1 + off);
    float4 t4 = *(const float4*)(wv2 + off);
    a0 += o4.x*k4.x + o4.y*k4.y + o4.z*k4.z + o4.w*k4.w;
    a1 += o4.x*l4.x + o4.y*l4.y + o4.z*l4.z + o4.w*l4.w;
    a2 += o4.x*c4.x + o4.y*c4.y + o4.z*c4.z + o4.w*c4.w;
    a3 += o4.x*t4.x + o4.y*t4.y + o4.z*t4.z + o4.w*t4.w;
  }
  a0 = wredsum(a0); a1 = wredsum(a1); a2 = wredsum(a2); a3 = wredsum(a3);
  if (lane == 0) {
    ws[OFF_C + idx]         = a0 + ws[OFF_CST+0];
    ws[OFF_HV + idx]        = a1 + ws[OFF_CST+1];
    ws[OFF_HV + 1024 + idx] = a2 + ws[OFF_CST+2];
    ws[OFF_HV + 2048 + idx] = a3 + ws[OFF_CST+3];
  }
}

// ---- K3: 128r x FULL-512s tile (softmax-complete per block) ----------------
// grid (b 2, rtile 4, l 103); 1024 thr = 16 waves (wr 2 x wc 8), wave 64r x 64s.
__global__ __launch_bounds__(1024, 4) void k_attn(
    const float* __restrict__ laws, const u16* __restrict__ kqB,
    const int* __restrict__ mask, float* __restrict__ ws,
    const float* __restrict__ bld, const float* __restrict__ wl1,
    const float* __restrict__ bad, const float* __restrict__ wa1,
    const float* __restrict__ btd, const float* __restrict__ wt1) {
  __shared__ u16 Abuf[2][5120];    // 1 kt (32 k) x 128 rows (+8 pad), dbuf, 20 KB
  __shared__ f32x4 redS[8][128];   // [wc][row], 16 KB
  const int tid = threadIdx.x, lane = tid & 63, w = tid >> 6;
  const int c4 = lane & 15, q4 = lane >> 4, wr = w >> 3, wc = w & 7;
  const int b = blockIdx.x, rtile = blockIdx.y, l = blockIdx.z;

  // A staging: thread -> (row sr 0..127, float4 seg sq 0..7); 32 floats/row/kt
  const int sr = tid >> 3, sq = tid & 7;
  const float* Asrc = laws + ((size_t)l * nR + rtile * 128 + sr) * nD + sq * 4;
  u16* Aw = &Abuf[0][sr * 40 + sq * 4];

  {  // prologue: stage kt=0 into buffer 0
    float4 g = *(const float4*)(Asrc);
    ushort4v u;
    u[0]=f2bf(g.x); u[1]=f2bf(g.y); u[2]=f2bf(g.z); u[3]=f2bf(g.w);
    *(ushort4v*)Aw = u;
  }

  // B fragment base: col = b*512 + wc*64 + ct*16 + c4, k-quad q4
  const u16* Bbase = kqB + ((size_t)q4 * 1024 + (size_t)b * nS + wc * 64 + c4) * 8;

  f32x4 acc[4][4];
#pragma unroll
  for (int rt = 0; rt < 4; ++rt)
#pragma unroll
    for (int ct = 0; ct < 4; ++ct) acc[rt][ct] = (f32x4){0.f,0.f,0.f,0.f};
  __syncthreads();

  for (int kt = 0; kt < 24; ++kt) {
    float4 g; const bool more = kt < 23;
    if (more) g = *(const float4*)(Asrc + (kt + 1) * 32);
    bf16x8 bfr[4];
#pragma unroll
    for (int ct = 0; ct < 4; ++ct)
      bfr[ct] = *(const bf16x8*)(Bbase + ((size_t)kt << 15) + (ct << 7));
    const u16* Ab = &Abuf[kt & 1][0];
    bf16x8 af[4];
#pragma unroll
    for (int rt = 0; rt < 4; ++rt)
      af[rt] = *(const bf16x8*)&Ab[(wr * 64 + rt * 16 + c4) * 40 + q4 * 8];
#pragma unroll
    for (int rt = 0; rt < 4; ++rt)
#pragma unroll
      for (int ct = 0; ct < 4; ++ct)
        acc[rt][ct] = __builtin_amdgcn_mfma_f32_16x16x32_bf16(af[rt], bfr[ct],
                                                              acc[rt][ct], 0, 0, 0);
    if (more) {
      ushort4v u;
      u[0]=f2bf(g.x); u[1]=f2bf(g.y); u[2]=f2bf(g.z); u[3]=f2bf(g.w);
      *(ushort4v*)(Aw + ((kt + 1) & 1) * 5120) = u;
    }
    __syncthreads();
  }

  // ---- per-col scalars: s = wc*64 + ct*16 + c4 (full 0..511 across waves) --
  const float* cp  = ws + OFF_C + (size_t)b * nS;
  const float* hlp = ws + OFF_HV + (size_t)b * nS;
  const float* hap = ws + OFF_HV + 1024 + (size_t)b * nS;
  const float* htp = ws + OFF_HV + 2048 + (size_t)b * nS;
  float cc[4], hl[4], ha[4], ht[4], ma[4];
#pragma unroll
  for (int ct = 0; ct < 4; ++ct) {
    int s = wc * 64 + ct * 16 + c4;
    cc[ct] = cp[s]; hl[ct] = hlp[s]; ha[ct] = hap[s]; ht[ct] = htp[s];
    ma[ct] = (1.0f - (float)mask[b * nS + s]) * -10000.0f;
  }

  // ---- exp (logits bounded; masked -> underflow 0) + 4 weighted row sums ---
#pragma unroll
  for (int rt = 0; rt < 4; ++rt) {
#pragma unroll
    for (int reg = 0; reg < 4; ++reg) {
      float sse = 0.f, spl = 0.f, spa = 0.f, spt = 0.f;
#pragma unroll
      for (int ct = 0; ct < 4; ++ct) {
        float x = (acc[rt][ct][reg] + cc[ct]) * INV_SQRT_D + ma[ct];
        float e = __expf(x);
        sse += e; spl += e * hl[ct]; spa += e * ha[ct]; spt += e * ht[ct];
      }
#pragma unroll
      for (int o = 1; o < 16; o <<= 1) {
        sse += __shfl_xor(sse, o);
        spl += __shfl_xor(spl, o);
        spa += __shfl_xor(spa, o);
        spt += __shfl_xor(spt, o);
      }
      if (c4 == 0)
        redS[wc][wr * 64 + rt * 16 + q4 * 4 + reg] = (f32x4){sse, spl, spa, spt};
    }
  }
  __syncthreads();

  // ---- finalize on waves 0,1: row = w*64 + lane ----------------------------
  if (w < 2) {
    int row = w * 64 + lane;
    f32x4 t = (f32x4){0.f,0.f,0.f,0.f};
#pragma unroll
    for (int wci = 0; wci < 8; ++wci) t += redS[wci][row];
    float inv = 1.0f / t[0];
    int r = rtile * 128 + row;
    float cl = tanhf(t[1] * inv + bld[0]) * wl1[r];
    float ca = tanhf(t[2] * inv + bad[0]) * wa1[r];
    float ctv = tanhf(t[3] * inv + btd[0]) * wt1[r];
#pragma unroll
    for (int o = 1; o < 64; o <<= 1) {
      cl += __shfl_xor(cl, o);
      ca += __shfl_xor(ca, o);
      ctv += __shfl_xor(ctv, o);
    }
    if (lane == 0) {
      float* sums = ws + OFF_SUM;
      atomicAdd(&sums[b * nL + l], cl);
      atomicAdd(&sums[nB * nL + b * nL + l], ca);
      atomicAdd(&sums[2 * nB * nL + b * nL + l], ctv);
    }
  }
}

// ---- K4: finalize heads ----------------------------------------------------
__global__ void k_final(const float* __restrict__ ws, float* __restrict__ out,
                        const float* __restrict__ bl1, const float* __restrict__ ba1,
                        const float* __restrict__ Wa2, const float* __restrict__ ba2,
                        const float* __restrict__ bt1, const float* __restrict__ Wt2,
                        const float* __restrict__ bt2) {
  __shared__ float abl[nB * nL], tbl[nB * nL];
  int t = threadIdx.x;
  const float* sl = ws + OFF_SUM;
  const float* sa = sl + nB * nL;
  const float* st = sa + nB * nL;
  if (t < nB * nL) {
    out[t] = sl[t] + bl1[0];
    abl[t] = tanhf(sa[t] + ba1[0]);
    tbl[t] = tanhf(st[t] + bt1[0]);
  }
  __syncthreads();
  for (int idx = t; idx < nB * 119; idx += 256) {
    int b = idx / 119, j = idx % 119;
    float a = ba2[j];
    for (int ll = 0; ll < nL; ++ll) a += Wa2[j * nL + ll] * abl[b * nL + ll];
    out[nB * nL + idx] = a;
  }
  for (int idx = t; idx < nB * 11; idx += 256) {
    int b = idx / 11, j = idx % 11;
    float a = bt2[j];
    for (int ll = 0; ll < nL; ++ll) a += Wt2[j * nL + ll] * tbl[b * nL + ll];
    out[nB * nL + nB * 119 + idx] = a;
  }
}

extern "C" void kernel_launch(void* const* d_in, const int* in_sizes, int n_in,
                              void* d_out, int out_size, void* d_ws, size_t ws_size,
                              hipStream_t stream) {
  (void)in_sizes; (void)n_in; (void)out_size; (void)ws_size;
  const float* outp = (const float*)d_in[0];
  const int*   mask = (const int*)d_in[1];
  const float* laws = (const float*)d_in[2];
  const float* Wq = (const float*)d_in[3];  const float* bq = (const float*)d_in[4];
  const float* Wk = (const float*)d_in[5];  const float* bk = (const float*)d_in[6];
  const float* Wv = (const float*)d_in[7];  const float* bv = (const float*)d_in[8];
  const float* wld = (const float*)d_in[9];  const float* bld = (const float*)d_in[10];
  const float* wl1 = (const float*)d_in[11]; const float* bl1 = (const float*)d_in[12];
  const float* wad = (const float*)d_in[13]; const float* bad = (const float*)d_in[14];
  const float* wa1 = (const float*)d_in[15]; const float* ba1 = (const float*)d_in[16];
  const float* Wa2 = (const float*)d_in[17]; const float* ba2 = (const float*)d_in[18];
  const float* wtd = (const float*)d_in[19]; const float* btd = (const float*)d_in[20];
  const float* wt1 = (const float*)d_in[21]; const float* bt1 = (const float*)d_in[22];
  const float* Wt2 = (const float*)d_in[23]; const float* bt2 = (const float*)d_in[24];
  float* ws = (float*)d_ws;
  float* fout = (float*)d_out;
  u16* wqb  = (u16*)(ws + OFF_WQB);
  u16* wkb  = (u16*)(ws + OFF_WKB);
  u16* outb = (u16*)(ws + OFF_OUTB);
  u16* Mbf  = (u16*)(ws + OFF_MBF);
  u16* kqB  = (u16*)(ws + OFF_KQB);   // aliases wqb/wkb region (dead by then)

  // 1) row-dots + consts + zero SUM
  k_prep<<<193, 256, 0, stream>>>(Wq, Wk, Wv, bq, bk, bv, wld, wad, wtd, ws);
  // 2) pack Wq, Wk, out -> bf16
  k_pack<<<480, 256, 0, stream>>>(Wq, Wk, outp, wqb, wkb, outb);
  // 3) M = Wq @ Wk^T (bf16 MFMA)
  mm_bf<<<dim3(6, 6), 512, 0, stream>>>(wqb, wkb, Mbf, nullptr, 0);
  // 4) kq = out @ M^T + qbk -> kqB frag layout (overwrites wqb/wkb)
  mm_bf<<<dim3(6, 8), 512, 0, stream>>>(outb, Mbf, kqB, ws + OFF_QBK, 1);
  // 5) per-(b,s) scalars
  k_chv<<<256, 256, 0, stream>>>(outp, ws);
  // 6) fused scores + full-row softmax + heads (block spans all 512 s)
  k_attn<<<dim3(nB, 4, nL), 1024, 0, stream>>>(laws, kqB, mask, ws,
                                               bld, wl1, bad, wa1, btd, wt1);
  // 7) output heads
  k_final<<<1, 256, 0, stream>>>(ws, fout, bl1, ba1, Wa2, ba2, bt1, Wt2, bt2);
}

// Round 6
// 460.197 us; speedup vs baseline: 3.8706x; 1.1164x over previous
//
#include <hip/hip_runtime.h>

static constexpr int nL = 103, nR = 512, nB = 2, nS = 512, nD = 768;
static constexpr float INV_SQRT_D = 0.03608439182435161f; // 1/sqrt(768)

typedef short bf16x8 __attribute__((ext_vector_type(8)));
typedef float f32x4 __attribute__((ext_vector_type(4)));
typedef unsigned short u16;
typedef unsigned short ushort4v __attribute__((ext_vector_type(4)));
typedef unsigned short ushort8v __attribute__((ext_vector_type(8)));

// ws layout (float offsets). Total ~4.16 MiB.
static constexpr size_t OFF_OUTB = 0;                  // 1024x768 bf16 = 393216 fl
static constexpr size_t OFF_MBF  = 393216;             // 768x768 bf16 = 294912 fl
static constexpr size_t OFF_KQB  = 688128;             // 96*1024*8 u16 = 393216 fl
static constexpr size_t OFF_QBK  = 1081344;            // 768 : Wq@bk
static constexpr size_t OFF_WKBQ = OFF_QBK + 768;      // 768 : Wk@bq
static constexpr size_t OFF_WV3  = OFF_WKBQ + 768;     // 3*768 : Wv@{wld,wad,wtd}
static constexpr size_t OFF_CST  = OFF_WV3 + 2304;     // 4
static constexpr size_t OFF_C    = OFF_CST + 4;        // 1024
static constexpr size_t OFF_HV   = OFF_C + 1024;       // 3*1024
static constexpr size_t OFF_SUM  = OFF_HV + 3072;      // 3*nB*nL = 618

__device__ inline float wredsum(float v) {
#pragma unroll
  for (int o = 32; o; o >>= 1) v += __shfl_xor(v, o);
  return v;
}

__device__ inline u16 f2bf(float f) {  // RNE fp32 -> bf16
  unsigned u = __builtin_bit_cast(unsigned, f);
  u += 0x7FFFu + ((u >> 16) & 1u);
  return (u16)(u >> 16);
}

__device__ inline bf16x8 cvt8(float4 a, float4 b) {
  ushort8v u;
  u[0]=f2bf(a.x); u[1]=f2bf(a.y); u[2]=f2bf(a.z); u[3]=f2bf(a.w);
  u[4]=f2bf(b.x); u[5]=f2bf(b.y); u[6]=f2bf(b.z); u[7]=f2bf(b.w);
  return __builtin_bit_cast(bf16x8, u);
}

// ---- K0: row-dots + consts + zero SUM + pack outp->bf16 --------------------
__global__ __launch_bounds__(256) void k_prep(
    const float* __restrict__ Wq, const float* __restrict__ Wk,
    const float* __restrict__ Wv, const float* __restrict__ bq,
    const float* __restrict__ bk, const float* __restrict__ bv,
    const float* __restrict__ wld, const float* __restrict__ wad,
    const float* __restrict__ wtd, const float* __restrict__ outp,
    float* __restrict__ ws) {
  int tid = threadIdx.x, lane = tid & 63, w = tid >> 6;
  int bid = blockIdx.x;
  if (bid < 192) {
    int row = bid * 4 + w;
    const float* wqr = Wq + (size_t)row * nD;
    const float* wkr = Wk + (size_t)row * nD;
    const float* wvr = Wv + (size_t)row * nD;
    float dq = 0.f, dk = 0.f, d0 = 0.f, d1 = 0.f, d2 = 0.f;
#pragma unroll
    for (int k = 0; k < 3; ++k) {
      int off = lane * 4 + k * 256;
      float4 q4 = *(const float4*)(wqr + off);
      float4 k4 = *(const float4*)(wkr + off);
      float4 v4 = *(const float4*)(wvr + off);
      float4 bk4 = *(const float4*)(bk + off);
      float4 bq4 = *(const float4*)(bq + off);
      float4 l4 = *(const float4*)(wld + off);
      float4 a4 = *(const float4*)(wad + off);
      float4 t4 = *(const float4*)(wtd + off);
      dq += q4.x*bk4.x + q4.y*bk4.y + q4.z*bk4.z + q4.w*bk4.w;
      dk += k4.x*bq4.x + k4.y*bq4.y + k4.z*bq4.z + k4.w*bq4.w;
      d0 += v4.x*l4.x + v4.y*l4.y + v4.z*l4.z + v4.w*l4.w;
      d1 += v4.x*a4.x + v4.y*a4.y + v4.z*a4.z + v4.w*a4.w;
      d2 += v4.x*t4.x + v4.y*t4.y + v4.z*t4.z + v4.w*t4.w;
    }
    dq = wredsum(dq); dk = wredsum(dk);
    d0 = wredsum(d0); d1 = wredsum(d1); d2 = wredsum(d2);
    if (lane == 0) {
      ws[OFF_QBK + row] = dq;
      ws[OFF_WKBQ + row] = dk;
      ws[OFF_WV3 + row] = d0;
      ws[OFF_WV3 + 768 + row] = d1;
      ws[OFF_WV3 + 1536 + row] = d2;
    }
  } else if (bid == 192) {
    if (tid < 64) {
      float c0 = 0.f, c1 = 0.f, c2 = 0.f, c3 = 0.f;
      for (int j = lane; j < nD; j += 64) {
        c0 += bq[j]*bk[j]; c1 += bv[j]*wld[j]; c2 += bv[j]*wad[j]; c3 += bv[j]*wtd[j];
      }
      c0 = wredsum(c0); c1 = wredsum(c1); c2 = wredsum(c2); c3 = wredsum(c3);
      if (lane == 0) {
        ws[OFF_CST+0] = c0; ws[OFF_CST+1] = c1; ws[OFF_CST+2] = c2; ws[OFF_CST+3] = c3;
      }
    }
    for (int i = tid; i < 3 * nB * nL; i += 256) ws[OFF_SUM + i] = 0.f;
  } else {
    // pack outp -> outb bf16: blocks 193..384, 4096 fl per block
    u16* outb = (u16*)(ws + OFF_OUTB);
    size_t e = ((size_t)(bid - 193) * 256 + tid) * 16;
    float4 f0 = *(const float4*)(outp + e);
    float4 f1 = *(const float4*)(outp + e + 4);
    float4 f2 = *(const float4*)(outp + e + 8);
    float4 f3 = *(const float4*)(outp + e + 12);
    *(ushort8v*)(outb + e)     = __builtin_bit_cast(ushort8v, cvt8(f0, f1));
    *(ushort8v*)(outb + e + 8) = __builtin_bit_cast(ushort8v, cvt8(f2, f3));
  }
}

// ---- K1: M = Wq @ Wk^T (direct-fragment MFMA, no LDS) + fused k_chv --------
// blocks 0..143: 64x64 M-tile (4 waves, wave 32x32). blocks 144..399: chv.
__global__ __launch_bounds__(256) void k_mmM_chv(
    const float* __restrict__ Wq, const float* __restrict__ Wk,
    const float* __restrict__ outp, float* __restrict__ ws) {
  int tid = threadIdx.x, lane = tid & 63, w = tid >> 6;
  int bid = blockIdx.x;
  if (bid < 144) {
    u16* Mbf = (u16*)(ws + OFF_MBF);
    const int ti = bid / 12, tj = bid % 12;
    const int c4 = lane & 15, q4 = lane >> 4, wr = w >> 1, wc = w & 1;
    f32x4 acc[2][2];
#pragma unroll
    for (int i = 0; i < 2; ++i)
#pragma unroll
      for (int j = 0; j < 2; ++j) acc[i][j] = (f32x4){0.f,0.f,0.f,0.f};
    const float* Ab[2]; const float* Bb[2];
#pragma unroll
    for (int i = 0; i < 2; ++i)
      Ab[i] = Wq + (size_t)(ti*64 + wr*32 + i*16 + c4) * nD + q4*8;
#pragma unroll
    for (int j = 0; j < 2; ++j)
      Bb[j] = Wk + (size_t)(tj*64 + wc*32 + j*16 + c4) * nD + q4*8;
    for (int kt = 0; kt < 24; ++kt) {
      bf16x8 af[2], bf[2];
#pragma unroll
      for (int i = 0; i < 2; ++i)
        af[i] = cvt8(*(const float4*)(Ab[i] + kt*32), *(const float4*)(Ab[i] + kt*32 + 4));
#pragma unroll
      for (int j = 0; j < 2; ++j)
        bf[j] = cvt8(*(const float4*)(Bb[j] + kt*32), *(const float4*)(Bb[j] + kt*32 + 4));
#pragma unroll
      for (int i = 0; i < 2; ++i)
#pragma unroll
        for (int j = 0; j < 2; ++j)
          acc[i][j] = __builtin_amdgcn_mfma_f32_16x16x32_bf16(af[i], bf[j], acc[i][j], 0, 0, 0);
    }
#pragma unroll
    for (int i = 0; i < 2; ++i)
#pragma unroll
      for (int j = 0; j < 2; ++j) {
        int n = tj*64 + wc*32 + j*16 + c4;
#pragma unroll
        for (int reg = 0; reg < 4; ++reg) {
          int m = ti*64 + wr*32 + i*16 + q4*4 + reg;
          Mbf[(size_t)m * nD + n] = f2bf(acc[i][j][reg]);
        }
      }
  } else {
    // chv: wave per (b,s) row
    int idx = (bid - 144) * 4 + w;
    const float* row = outp + (size_t)idx * nD;
    const float* wkbq = ws + OFF_WKBQ;
    const float* wv0 = ws + OFF_WV3;
    const float* wv1 = ws + OFF_WV3 + 768;
    const float* wv2 = ws + OFF_WV3 + 1536;
    float a0 = 0.f, a1 = 0.f, a2 = 0.f, a3 = 0.f;
#pragma unroll
    for (int k = 0; k < 3; ++k) {
      int off = lane * 4 + k * 256;
      float4 o4 = *(const float4*)(row + off);
      float4 k4 = *(const float4*)(wkbq + off);
      float4 l4 = *(const float4*)(wv0 + off);
      float4 c4v = *(const float4*)(wv1 + off);
      float4 t4 = *(const float4*)(wv2 + off);
      a0 += o4.x*k4.x + o4.y*k4.y + o4.z*k4.z + o4.w*k4.w;
      a1 += o4.x*l4.x + o4.y*l4.y + o4.z*l4.z + o4.w*l4.w;
      a2 += o4.x*c4v.x + o4.y*c4v.y + o4.z*c4v.z + o4.w*c4v.w;
      a3 += o4.x*t4.x + o4.y*t4.y + o4.z*t4.z + o4.w*t4.w;
    }
    a0 = wredsum(a0); a1 = wredsum(a1); a2 = wredsum(a2); a3 = wredsum(a3);
    if (lane == 0) {
      ws[OFF_C + idx]         = a0 + ws[OFF_CST+0];
      ws[OFF_HV + idx]        = a1 + ws[OFF_CST+1];
      ws[OFF_HV + 1024 + idx] = a2 + ws[OFF_CST+2];
      ws[OFF_HV + 2048 + idx] = a3 + ws[OFF_CST+3];
    }
  }
}

// ---- K2: kq = outb @ Mbf^T + qbk -> kqB frag layout (no LDS, no barriers) --
__global__ __launch_bounds__(256) void k_mkq(float* __restrict__ ws) {
  const u16* outb = (const u16*)(ws + OFF_OUTB);
  const u16* Mbf  = (const u16*)(ws + OFF_MBF);
  u16* kqB = (u16*)(ws + OFF_KQB);
  const float* qbk = ws + OFF_QBK;
  int tid = threadIdx.x, lane = tid & 63, w = tid >> 6;
  const int c4 = lane & 15, q4 = lane >> 4, wr = w >> 1, wc = w & 1;
  const int ti = blockIdx.y, tj = blockIdx.x;
  f32x4 acc[2][2];
#pragma unroll
  for (int i = 0; i < 2; ++i)
#pragma unroll
    for (int j = 0; j < 2; ++j) acc[i][j] = (f32x4){0.f,0.f,0.f,0.f};
  const u16* Ab[2]; const u16* Bb[2];
#pragma unroll
  for (int i = 0; i < 2; ++i)
    Ab[i] = outb + (size_t)(ti*64 + wr*32 + i*16 + c4) * nD + q4*8;
#pragma unroll
  for (int j = 0; j < 2; ++j)
    Bb[j] = Mbf + (size_t)(tj*64 + wc*32 + j*16 + c4) * nD + q4*8;
  for (int kt = 0; kt < 24; ++kt) {
    bf16x8 af[2], bf[2];
#pragma unroll
    for (int i = 0; i < 2; ++i) af[i] = *(const bf16x8*)(Ab[i] + kt*32);
#pragma unroll
    for (int j = 0; j < 2; ++j) bf[j] = *(const bf16x8*)(Bb[j] + kt*32);
#pragma unroll
    for (int i = 0; i < 2; ++i)
#pragma unroll
      for (int j = 0; j < 2; ++j)
        acc[i][j] = __builtin_amdgcn_mfma_f32_16x16x32_bf16(af[i], bf[j], acc[i][j], 0, 0, 0);
  }
#pragma unroll
  for (int i = 0; i < 2; ++i)
#pragma unroll
    for (int j = 0; j < 2; ++j) {
      int n = tj*64 + wc*32 + j*16 + c4;
      float bb = qbk[n];
#pragma unroll
      for (int reg = 0; reg < 4; ++reg) {
        int m = ti*64 + wr*32 + i*16 + q4*4 + reg;
        kqB[(((size_t)(n >> 3)) << 13) + ((size_t)m << 3) + (n & 7)] =
            f2bf(acc[i][j][reg] + bb);
      }
    }
}

// ---- K3: 64r x 512s tile; B-first issue order, distance-2 A pipeline -------
// grid (b 2, rt8 8, l 103); 512 thr = 8 waves, wave 64r x 64c (w = col chunk)
__global__ __launch_bounds__(512) void k_attn(
    const float* __restrict__ laws, const u16* __restrict__ kqB,
    const int* __restrict__ mask, float* __restrict__ ws,
    const float* __restrict__ bld, const float* __restrict__ wl1,
    const float* __restrict__ bad, const float* __restrict__ wa1,
    const float* __restrict__ btd, const float* __restrict__ wt1) {
  __shared__ u16 Abuf[2][64 * 40];   // 64 rows x 32 k bf16 (+pad), dbuf, 10 KB
  __shared__ f32x4 redS[8][64];      // 8 KB
  const int tid = threadIdx.x, lane = tid & 63, w = tid >> 6;
  const int c4 = lane & 15, q4 = lane >> 4;
  const int b = blockIdx.x, rt8 = blockIdx.y, l = blockIdx.z;

  // A staging: thread -> (row sr 0..63, float4 seg sq 0..7); 32 fl/row/kt
  const int sr = tid >> 3, sq = tid & 7;
  const float* Asrc = laws + ((size_t)l * nR + rt8 * 64 + sr) * nD + sq * 4;
  u16* Aw = &Abuf[0][sr * 40 + sq * 4];

  // B fragment base: col s = w*64 + ct*16 + c4
  const u16* Bbase = kqB + ((size_t)q4 * 1024 + (size_t)b * nS + w * 64 + c4) * 8;

  // prologue: A(0) -> buf0; B(0) -> Bc; A(1) held in g1
  float4 g0 = *(const float4*)(Asrc);
  bf16x8 Bc[4];
#pragma unroll
  for (int ct = 0; ct < 4; ++ct) Bc[ct] = *(const bf16x8*)(Bbase + ct * 128);
  float4 g1 = *(const float4*)(Asrc + 32);
  {
    ushort4v u;
    u[0]=f2bf(g0.x); u[1]=f2bf(g0.y); u[2]=f2bf(g0.z); u[3]=f2bf(g0.w);
    *(ushort4v*)Aw = u;
  }
  f32x4 acc[4][4];
#pragma unroll
  for (int rt = 0; rt < 4; ++rt)
#pragma unroll
    for (int ct = 0; ct < 4; ++ct) acc[rt][ct] = (f32x4){0.f,0.f,0.f,0.f};
  __syncthreads();

#pragma unroll
  for (int kt = 0; kt < 24; ++kt) {
    bf16x8 Bn[4];
    float4 g2;
    if (kt < 23) {             // B for kt+1 issued FIRST (in-order vmcnt!)
#pragma unroll
      for (int ct = 0; ct < 4; ++ct)
        Bn[ct] = *(const bf16x8*)(Bbase + (size_t)(kt + 1) * 32768 + ct * 128);
    }
    if (kt < 22)               // A for kt+2 (distance-2)
      g2 = *(const float4*)(Asrc + (size_t)(kt + 2) * 32);
    const u16* Ab = &Abuf[kt & 1][0];
    bf16x8 af[4];
#pragma unroll
    for (int rt = 0; rt < 4; ++rt)
      af[rt] = *(const bf16x8*)&Ab[(rt * 16 + c4) * 40 + q4 * 8];
#pragma unroll
    for (int rt = 0; rt < 4; ++rt)
#pragma unroll
      for (int ct = 0; ct < 4; ++ct)
        acc[rt][ct] = __builtin_amdgcn_mfma_f32_16x16x32_bf16(af[rt], Bc[ct],
                                                              acc[rt][ct], 0, 0, 0);
    if (kt < 23) {             // store A(kt+1): its load is ~1 iteration old
      ushort4v u;
      u[0]=f2bf(g1.x); u[1]=f2bf(g1.y); u[2]=f2bf(g1.z); u[3]=f2bf(g1.w);
      *(ushort4v*)(Aw + ((kt + 1) & 1) * (64 * 40)) = u;
      g1 = g2;
#pragma unroll
      for (int ct = 0; ct < 4; ++ct) Bc[ct] = Bn[ct];
    }
    __syncthreads();
  }

  // ---- per-col scalars: s = w*64 + ct*16 + c4 ------------------------------
  const float* cp  = ws + OFF_C + (size_t)b * nS;
  const float* hlp = ws + OFF_HV + (size_t)b * nS;
  const float* hap = ws + OFF_HV + 1024 + (size_t)b * nS;
  const float* htp = ws + OFF_HV + 2048 + (size_t)b * nS;
  float cc[4], hl[4], ha[4], ht[4], ma[4];
#pragma unroll
  for (int ct = 0; ct < 4; ++ct) {
    int s = w * 64 + ct * 16 + c4;
    cc[ct] = cp[s]; hl[ct] = hlp[s]; ha[ct] = hap[s]; ht[ct] = htp[s];
    ma[ct] = (1.0f - (float)mask[b * nS + s]) * -10000.0f;
  }

  // ---- exp (logits bounded; masked -> underflow 0) + 4 weighted row sums ---
#pragma unroll
  for (int rt = 0; rt < 4; ++rt) {
#pragma unroll
    for (int reg = 0; reg < 4; ++reg) {
      float sse = 0.f, spl = 0.f, spa = 0.f, spt = 0.f;
#pragma unroll
      for (int ct = 0; ct < 4; ++ct) {
        float x = (acc[rt][ct][reg] + cc[ct]) * INV_SQRT_D + ma[ct];
        float e = __expf(x);
        sse += e; spl += e * hl[ct]; spa += e * ha[ct]; spt += e * ht[ct];
      }
#pragma unroll
      for (int o = 1; o < 16; o <<= 1) {
        sse += __shfl_xor(sse, o);
        spl += __shfl_xor(spl, o);
        spa += __shfl_xor(spa, o);
        spt += __shfl_xor(spt, o);
      }
      if (c4 == 0)
        redS[w][rt * 16 + q4 * 4 + reg] = (f32x4){sse, spl, spa, spt};
    }
  }
  __syncthreads();

  // ---- finalize on wave 0: one row per lane --------------------------------
  if (w == 0) {
    int row = lane;
    f32x4 t = (f32x4){0.f,0.f,0.f,0.f};
#pragma unroll
    for (int wc = 0; wc < 8; ++wc) t += redS[wc][row];
    float inv = 1.0f / t[0];
    int r = rt8 * 64 + row;
    float cl = tanhf(t[1] * inv + bld[0]) * wl1[r];
    float ca = tanhf(t[2] * inv + bad[0]) * wa1[r];
    float ctv = tanhf(t[3] * inv + btd[0]) * wt1[r];
#pragma unroll
    for (int o = 1; o < 64; o <<= 1) {
      cl += __shfl_xor(cl, o);
      ca += __shfl_xor(ca, o);
      ctv += __shfl_xor(ctv, o);
    }
    if (lane == 0) {
      float* sums = ws + OFF_SUM;
      atomicAdd(&sums[b * nL + l], cl);
      atomicAdd(&sums[nB * nL + b * nL + l], ca);
      atomicAdd(&sums[2 * nB * nL + b * nL + l], ctv);
    }
  }
}

// ---- K4: finalize heads ----------------------------------------------------
__global__ void k_final(const float* __restrict__ ws, float* __restrict__ out,
                        const float* __restrict__ bl1, const float* __restrict__ ba1,
                        const float* __restrict__ Wa2, const float* __restrict__ ba2,
                        const float* __restrict__ bt1, const float* __restrict__ Wt2,
                        const float* __restrict__ bt2) {
  __shared__ float abl[nB * nL], tbl[nB * nL];
  int t = threadIdx.x;
  const float* sl = ws + OFF_SUM;
  const float* sa = sl + nB * nL;
  const float* st = sa + nB * nL;
  if (t < nB * nL) {
    out[t] = sl[t] + bl1[0];
    abl[t] = tanhf(sa[t] + ba1[0]);
    tbl[t] = tanhf(st[t] + bt1[0]);
  }
  __syncthreads();
  for (int idx = t; idx < nB * 119; idx += 256) {
    int b = idx / 119, j = idx % 119;
    float a = ba2[j];
    for (int ll = 0; ll < nL; ++ll) a += Wa2[j * nL + ll] * abl[b * nL + ll];
    out[nB * nL + idx] = a;
  }
  for (int idx = t; idx < nB * 11; idx += 256) {
    int b = idx / 11, j = idx % 11;
    float a = bt2[j];
    for (int ll = 0; ll < nL; ++ll) a += Wt2[j * nL + ll] * tbl[b * nL + ll];
    out[nB * nL + nB * 119 + idx] = a;
  }
}

extern "C" void kernel_launch(void* const* d_in, const int* in_sizes, int n_in,
                              void* d_out, int out_size, void* d_ws, size_t ws_size,
                              hipStream_t stream) {
  (void)in_sizes; (void)n_in; (void)out_size; (void)ws_size;
  const float* outp = (const float*)d_in[0];
  const int*   mask = (const int*)d_in[1];
  const float* laws = (const float*)d_in[2];
  const float* Wq = (const float*)d_in[3];  const float* bq = (const float*)d_in[4];
  const float* Wk = (const float*)d_in[5];  const float* bk = (const float*)d_in[6];
  const float* Wv = (const float*)d_in[7];  const float* bv = (const float*)d_in[8];
  const float* wld = (const float*)d_in[9];  const float* bld = (const float*)d_in[10];
  const float* wl1 = (const float*)d_in[11]; const float* bl1 = (const float*)d_in[12];
  const float* wad = (const float*)d_in[13]; const float* bad = (const float*)d_in[14];
  const float* wa1 = (const float*)d_in[15]; const float* ba1 = (const float*)d_in[16];
  const float* Wa2 = (const float*)d_in[17]; const float* ba2 = (const float*)d_in[18];
  const float* wtd = (const float*)d_in[19]; const float* btd = (const float*)d_in[20];
  const float* wt1 = (const float*)d_in[21]; const float* bt1 = (const float*)d_in[22];
  const float* Wt2 = (const float*)d_in[23]; const float* bt2 = (const float*)d_in[24];
  float* ws = (float*)d_ws;
  float* fout = (float*)d_out;
  u16* kqB = (u16*)(ws + OFF_KQB);

  // 1) row-dots + consts + zero SUM + pack outp -> bf16
  k_prep<<<385, 256, 0, stream>>>(Wq, Wk, Wv, bq, bk, bv, wld, wad, wtd, outp, ws);
  // 2) M = Wq @ Wk^T (direct-frag MFMA) + chv
  k_mmM_chv<<<400, 256, 0, stream>>>(Wq, Wk, outp, ws);
  // 3) kq = outb @ M^T + qbk -> kqB frag layout
  k_mkq<<<dim3(12, 16), 256, 0, stream>>>(ws);
  // 4) fused scores + full-row softmax + heads
  k_attn<<<dim3(nB, 8, nL), 512, 0, stream>>>(laws, kqB, mask, ws,
                                              bld, wl1, bad, wa1, btd, wt1);
  // 5) output heads
  k_final<<<1, 256, 0, stream>>>(ws, fout, bl1, ba1, Wa2, ba2, bt1, Wt2, bt2);
}

// Round 7
// 459.904 us; speedup vs baseline: 3.8731x; 1.0006x over previous
//
#include <hip/hip_runtime.h>

static constexpr int nL = 103, nR = 512, nB = 2, nS = 512, nD = 768;
static constexpr float INV_SQRT_D = 0.03608439182435161f; // 1/sqrt(768)

typedef short bf16x8 __attribute__((ext_vector_type(8)));
typedef float f32x4 __attribute__((ext_vector_type(4)));
typedef unsigned short u16;
typedef unsigned short ushort4v __attribute__((ext_vector_type(4)));
typedef unsigned short ushort8v __attribute__((ext_vector_type(8)));

// ws layout (float offsets). Total ~4.16 MiB.
static constexpr size_t OFF_OUTB = 0;                  // 1024x768 bf16 = 393216 fl
static constexpr size_t OFF_MBF  = 393216;             // 768x768 bf16 = 294912 fl
static constexpr size_t OFF_KQB  = 688128;             // 96*1024*8 u16 = 393216 fl
static constexpr size_t OFF_QBK  = 1081344;            // 768 : Wq@bk
static constexpr size_t OFF_WKBQ = OFF_QBK + 768;      // 768 : Wk@bq
static constexpr size_t OFF_WV3  = OFF_WKBQ + 768;     // 3*768 : Wv@{wld,wad,wtd}
static constexpr size_t OFF_CST  = OFF_WV3 + 2304;     // 4
static constexpr size_t OFF_C    = OFF_CST + 4;        // 1024
static constexpr size_t OFF_HV   = OFF_C + 1024;       // 3*1024
static constexpr size_t OFF_SUM  = OFF_HV + 3072;      // 3*nB*nL = 618

__device__ inline float wredsum(float v) {
#pragma unroll
  for (int o = 32; o; o >>= 1) v += __shfl_xor(v, o);
  return v;
}

__device__ inline u16 f2bf(float f) {  // RNE fp32 -> bf16
  unsigned u = __builtin_bit_cast(unsigned, f);
  u += 0x7FFFu + ((u >> 16) & 1u);
  return (u16)(u >> 16);
}

__device__ inline bf16x8 cvt8(float4 a, float4 b) {
  ushort8v u;
  u[0]=f2bf(a.x); u[1]=f2bf(a.y); u[2]=f2bf(a.z); u[3]=f2bf(a.w);
  u[4]=f2bf(b.x); u[5]=f2bf(b.y); u[6]=f2bf(b.z); u[7]=f2bf(b.w);
  return __builtin_bit_cast(bf16x8, u);
}

// ---- K0: row-dots + consts + zero SUM + pack outp->bf16 --------------------
__global__ __launch_bounds__(256) void k_prep(
    const float* __restrict__ Wq, const float* __restrict__ Wk,
    const float* __restrict__ Wv, const float* __restrict__ bq,
    const float* __restrict__ bk, const float* __restrict__ bv,
    const float* __restrict__ wld, const float* __restrict__ wad,
    const float* __restrict__ wtd, const float* __restrict__ outp,
    float* __restrict__ ws) {
  int tid = threadIdx.x, lane = tid & 63, w = tid >> 6;
  int bid = blockIdx.x;
  if (bid < 192) {
    int row = bid * 4 + w;
    const float* wqr = Wq + (size_t)row * nD;
    const float* wkr = Wk + (size_t)row * nD;
    const float* wvr = Wv + (size_t)row * nD;
    float dq = 0.f, dk = 0.f, d0 = 0.f, d1 = 0.f, d2 = 0.f;
#pragma unroll
    for (int k = 0; k < 3; ++k) {
      int off = lane * 4 + k * 256;
      float4 q4 = *(const float4*)(wqr + off);
      float4 k4 = *(const float4*)(wkr + off);
      float4 v4 = *(const float4*)(wvr + off);
      float4 bk4 = *(const float4*)(bk + off);
      float4 bq4 = *(const float4*)(bq + off);
      float4 l4 = *(const float4*)(wld + off);
      float4 a4 = *(const float4*)(wad + off);
      float4 t4 = *(const float4*)(wtd + off);
      dq += q4.x*bk4.x + q4.y*bk4.y + q4.z*bk4.z + q4.w*bk4.w;
      dk += k4.x*bq4.x + k4.y*bq4.y + k4.z*bq4.z + k4.w*bq4.w;
      d0 += v4.x*l4.x + v4.y*l4.y + v4.z*l4.z + v4.w*l4.w;
      d1 += v4.x*a4.x + v4.y*a4.y + v4.z*a4.z + v4.w*a4.w;
      d2 += v4.x*t4.x + v4.y*t4.y + v4.z*t4.z + v4.w*t4.w;
    }
    dq = wredsum(dq); dk = wredsum(dk);
    d0 = wredsum(d0); d1 = wredsum(d1); d2 = wredsum(d2);
    if (lane == 0) {
      ws[OFF_QBK + row] = dq;
      ws[OFF_WKBQ + row] = dk;
      ws[OFF_WV3 + row] = d0;
      ws[OFF_WV3 + 768 + row] = d1;
      ws[OFF_WV3 + 1536 + row] = d2;
    }
  } else if (bid == 192) {
    if (tid < 64) {
      float c0 = 0.f, c1 = 0.f, c2 = 0.f, c3 = 0.f;
      for (int j = lane; j < nD; j += 64) {
        c0 += bq[j]*bk[j]; c1 += bv[j]*wld[j]; c2 += bv[j]*wad[j]; c3 += bv[j]*wtd[j];
      }
      c0 = wredsum(c0); c1 = wredsum(c1); c2 = wredsum(c2); c3 = wredsum(c3);
      if (lane == 0) {
        ws[OFF_CST+0] = c0; ws[OFF_CST+1] = c1; ws[OFF_CST+2] = c2; ws[OFF_CST+3] = c3;
      }
    }
    for (int i = tid; i < 3 * nB * nL; i += 256) ws[OFF_SUM + i] = 0.f;
  } else {
    // pack outp -> outb bf16: blocks 193..384, 4096 fl per block
    u16* outb = (u16*)(ws + OFF_OUTB);
    size_t e = ((size_t)(bid - 193) * 256 + tid) * 16;
    float4 f0 = *(const float4*)(outp + e);
    float4 f1 = *(const float4*)(outp + e + 4);
    float4 f2 = *(const float4*)(outp + e + 8);
    float4 f3 = *(const float4*)(outp + e + 12);
    *(ushort8v*)(outb + e)     = __builtin_bit_cast(ushort8v, cvt8(f0, f1));
    *(ushort8v*)(outb + e + 8) = __builtin_bit_cast(ushort8v, cvt8(f2, f3));
  }
}

// ---- K1: M = Wq @ Wk^T (direct-fragment MFMA, no LDS) + fused k_chv --------
__global__ __launch_bounds__(256) void k_mmM_chv(
    const float* __restrict__ Wq, const float* __restrict__ Wk,
    const float* __restrict__ outp, float* __restrict__ ws) {
  int tid = threadIdx.x, lane = tid & 63, w = tid >> 6;
  int bid = blockIdx.x;
  if (bid < 144) {
    u16* Mbf = (u16*)(ws + OFF_MBF);
    const int ti = bid / 12, tj = bid % 12;
    const int c4 = lane & 15, q4 = lane >> 4, wr = w >> 1, wc = w & 1;
    f32x4 acc[2][2];
#pragma unroll
    for (int i = 0; i < 2; ++i)
#pragma unroll
      for (int j = 0; j < 2; ++j) acc[i][j] = (f32x4){0.f,0.f,0.f,0.f};
    const float* Ab[2]; const float* Bb[2];
#pragma unroll
    for (int i = 0; i < 2; ++i)
      Ab[i] = Wq + (size_t)(ti*64 + wr*32 + i*16 + c4) * nD + q4*8;
#pragma unroll
    for (int j = 0; j < 2; ++j)
      Bb[j] = Wk + (size_t)(tj*64 + wc*32 + j*16 + c4) * nD + q4*8;
    for (int kt = 0; kt < 24; ++kt) {
      bf16x8 af[2], bf[2];
#pragma unroll
      for (int i = 0; i < 2; ++i)
        af[i] = cvt8(*(const float4*)(Ab[i] + kt*32), *(const float4*)(Ab[i] + kt*32 + 4));
#pragma unroll
      for (int j = 0; j < 2; ++j)
        bf[j] = cvt8(*(const float4*)(Bb[j] + kt*32), *(const float4*)(Bb[j] + kt*32 + 4));
#pragma unroll
      for (int i = 0; i < 2; ++i)
#pragma unroll
        for (int j = 0; j < 2; ++j)
          acc[i][j] = __builtin_amdgcn_mfma_f32_16x16x32_bf16(af[i], bf[j], acc[i][j], 0, 0, 0);
    }
#pragma unroll
    for (int i = 0; i < 2; ++i)
#pragma unroll
      for (int j = 0; j < 2; ++j) {
        int n = tj*64 + wc*32 + j*16 + c4;
#pragma unroll
        for (int reg = 0; reg < 4; ++reg) {
          int m = ti*64 + wr*32 + i*16 + q4*4 + reg;
          Mbf[(size_t)m * nD + n] = f2bf(acc[i][j][reg]);
        }
      }
  } else {
    // chv: wave per (b,s) row
    int idx = (bid - 144) * 4 + w;
    const float* row = outp + (size_t)idx * nD;
    const float* wkbq = ws + OFF_WKBQ;
    const float* wv0 = ws + OFF_WV3;
    const float* wv1 = ws + OFF_WV3 + 768;
    const float* wv2 = ws + OFF_WV3 + 1536;
    float a0 = 0.f, a1 = 0.f, a2 = 0.f, a3 = 0.f;
#pragma unroll
    for (int k = 0; k < 3; ++k) {
      int off = lane * 4 + k * 256;
      float4 o4 = *(const float4*)(row + off);
      float4 k4 = *(const float4*)(wkbq + off);
      float4 l4 = *(const float4*)(wv0 + off);
      float4 c4v = *(const float4*)(wv1 + off);
      float4 t4 = *(const float4*)(wv2 + off);
      a0 += o4.x*k4.x + o4.y*k4.y + o4.z*k4.z + o4.w*k4.w;
      a1 += o4.x*l4.x + o4.y*l4.y + o4.z*l4.z + o4.w*l4.w;
      a2 += o4.x*c4v.x + o4.y*c4v.y + o4.z*c4v.z + o4.w*c4v.w;
      a3 += o4.x*t4.x + o4.y*t4.y + o4.z*t4.z + o4.w*t4.w;
    }
    a0 = wredsum(a0); a1 = wredsum(a1); a2 = wredsum(a2); a3 = wredsum(a3);
    if (lane == 0) {
      ws[OFF_C + idx]         = a0 + ws[OFF_CST+0];
      ws[OFF_HV + idx]        = a1 + ws[OFF_CST+1];
      ws[OFF_HV + 1024 + idx] = a2 + ws[OFF_CST+2];
      ws[OFF_HV + 2048 + idx] = a3 + ws[OFF_CST+3];
    }
  }
}

// ---- K2: kq = outb @ Mbf^T + qbk -> kqB frag layout (no LDS, no barriers) --
__global__ __launch_bounds__(256) void k_mkq(float* __restrict__ ws) {
  const u16* outb = (const u16*)(ws + OFF_OUTB);
  const u16* Mbf  = (const u16*)(ws + OFF_MBF);
  u16* kqB = (u16*)(ws + OFF_KQB);
  const float* qbk = ws + OFF_QBK;
  int tid = threadIdx.x, lane = tid & 63, w = tid >> 6;
  const int c4 = lane & 15, q4 = lane >> 4, wr = w >> 1, wc = w & 1;
  const int ti = blockIdx.y, tj = blockIdx.x;
  f32x4 acc[2][2];
#pragma unroll
  for (int i = 0; i < 2; ++i)
#pragma unroll
    for (int j = 0; j < 2; ++j) acc[i][j] = (f32x4){0.f,0.f,0.f,0.f};
  const u16* Ab[2]; const u16* Bb[2];
#pragma unroll
  for (int i = 0; i < 2; ++i)
    Ab[i] = outb + (size_t)(ti*64 + wr*32 + i*16 + c4) * nD + q4*8;
#pragma unroll
  for (int j = 0; j < 2; ++j)
    Bb[j] = Mbf + (size_t)(tj*64 + wc*32 + j*16 + c4) * nD + q4*8;
  for (int kt = 0; kt < 24; ++kt) {
    bf16x8 af[2], bf[2];
#pragma unroll
    for (int i = 0; i < 2; ++i) af[i] = *(const bf16x8*)(Ab[i] + kt*32);
#pragma unroll
    for (int j = 0; j < 2; ++j) bf[j] = *(const bf16x8*)(Bb[j] + kt*32);
#pragma unroll
    for (int i = 0; i < 2; ++i)
#pragma unroll
      for (int j = 0; j < 2; ++j)
        acc[i][j] = __builtin_amdgcn_mfma_f32_16x16x32_bf16(af[i], bf[j], acc[i][j], 0, 0, 0);
  }
#pragma unroll
  for (int i = 0; i < 2; ++i)
#pragma unroll
    for (int j = 0; j < 2; ++j) {
      int n = tj*64 + wc*32 + j*16 + c4;
      float bb = qbk[n];
#pragma unroll
      for (int reg = 0; reg < 4; ++reg) {
        int m = ti*64 + wr*32 + i*16 + q4*4 + reg;
        kqB[(((size_t)(n >> 3)) << 13) + ((size_t)m << 3) + (n & 7)] =
            f2bf(acc[i][j][reg] + bb);
      }
    }
}

// ---- K3: 64r x 512s tile; 6-kt staged LDS A, barrier every 6 kt ------------
// grid (b 2, rt8 8, l 103); 512 thr = 8 waves, wave 64r x 64c (w = col chunk)
__global__ __launch_bounds__(512) void k_attn(
    const float* __restrict__ laws, const u16* __restrict__ kqB,
    const int* __restrict__ mask, float* __restrict__ ws,
    const float* __restrict__ bld, const float* __restrict__ wl1,
    const float* __restrict__ bad, const float* __restrict__ wa1,
    const float* __restrict__ btd, const float* __restrict__ wt1) {
  __shared__ u16 Abuf[64 * 200];     // 64 rows x (192 k + 8 pad) bf16 = 25 KB
  __shared__ f32x4 redS[8][64];      // 8 KB
  const int tid = threadIdx.x, lane = tid & 63, w = tid >> 6;
  const int c4 = lane & 15, q4 = lane >> 4;
  const int b = blockIdx.x, rt8 = blockIdx.y, l = blockIdx.z;

  // A staging: thread -> (row sr 0..63, seg sq 0..7); per stage 6 float4/thread
  // thread's k positions within stage: sq*4 + i*32, i = 0..5 (coalesced per i)
  const int sr = tid >> 3, sq = tid & 7;
  const float* Asrc = laws + ((size_t)l * nR + rt8 * 64 + sr) * nD + sq * 4;
  u16* Aw = &Abuf[sr * 200 + sq * 4];

  // B fragment base: col s = w*64 + ct*16 + c4, k-quad q4
  const u16* Bbase = kqB + ((size_t)q4 * 1024 + (size_t)b * nS + w * 64 + c4) * 8;

  f32x4 acc[4][4];
#pragma unroll
  for (int rt = 0; rt < 4; ++rt)
#pragma unroll
    for (int ct = 0; ct < 4; ++ct) acc[rt][ct] = (f32x4){0.f,0.f,0.f,0.f};

  // prologue: load + store stage 0
  float4 g[6];
#pragma unroll
  for (int i = 0; i < 6; ++i) g[i] = *(const float4*)(Asrc + i * 32);
#pragma unroll
  for (int i = 0; i < 6; ++i) {
    ushort4v u;
    u[0]=f2bf(g[i].x); u[1]=f2bf(g[i].y); u[2]=f2bf(g[i].z); u[3]=f2bf(g[i].w);
    *(ushort4v*)(Aw + i * 32) = u;
  }
  __syncthreads();

#pragma unroll
  for (int s = 0; s < 4; ++s) {
    if (s < 3) {   // issue next stage's loads; they get the whole 6-kt span
#pragma unroll
      for (int i = 0; i < 6; ++i)
        g[i] = *(const float4*)(Asrc + (s + 1) * 192 + i * 32);
    }
    // ---- 6-kt compute span: NO barriers inside -> B loads pipeline freely --
#pragma unroll
    for (int k6 = 0; k6 < 6; ++k6) {
      const int kt = s * 6 + k6;
      bf16x8 bf[4];
#pragma unroll
      for (int ct = 0; ct < 4; ++ct)
        bf[ct] = *(const bf16x8*)(Bbase + (size_t)kt * 32768 + ct * 128);
      bf16x8 af[4];
#pragma unroll
      for (int rt = 0; rt < 4; ++rt)
        af[rt] = *(const bf16x8*)&Abuf[(rt * 16 + c4) * 200 + k6 * 32 + q4 * 8];
#pragma unroll
      for (int rt = 0; rt < 4; ++rt)
#pragma unroll
        for (int ct = 0; ct < 4; ++ct)
          acc[rt][ct] = __builtin_amdgcn_mfma_f32_16x16x32_bf16(af[rt], bf[ct],
                                                                acc[rt][ct], 0, 0, 0);
    }
    __syncthreads();   // all waves done reading stage s
    if (s < 3) {
#pragma unroll
      for (int i = 0; i < 6; ++i) {
        ushort4v u;
        u[0]=f2bf(g[i].x); u[1]=f2bf(g[i].y); u[2]=f2bf(g[i].z); u[3]=f2bf(g[i].w);
        *(ushort4v*)(Aw + i * 32) = u;
      }
      __syncthreads(); // stage s+1 visible to all waves
    }
  }

  // ---- per-col scalars: s = w*64 + ct*16 + c4 ------------------------------
  const float* cp  = ws + OFF_C + (size_t)b * nS;
  const float* hlp = ws + OFF_HV + (size_t)b * nS;
  const float* hap = ws + OFF_HV + 1024 + (size_t)b * nS;
  const float* htp = ws + OFF_HV + 2048 + (size_t)b * nS;
  float cc[4], hl[4], ha[4], ht[4], ma[4];
#pragma unroll
  for (int ct = 0; ct < 4; ++ct) {
    int s = w * 64 + ct * 16 + c4;
    cc[ct] = cp[s]; hl[ct] = hlp[s]; ha[ct] = hap[s]; ht[ct] = htp[s];
    ma[ct] = (1.0f - (float)mask[b * nS + s]) * -10000.0f;
  }

  // ---- exp (logits bounded; masked -> underflow 0) + 4 weighted row sums ---
#pragma unroll
  for (int rt = 0; rt < 4; ++rt) {
#pragma unroll
    for (int reg = 0; reg < 4; ++reg) {
      float sse = 0.f, spl = 0.f, spa = 0.f, spt = 0.f;
#pragma unroll
      for (int ct = 0; ct < 4; ++ct) {
        float x = (acc[rt][ct][reg] + cc[ct]) * INV_SQRT_D + ma[ct];
        float e = __expf(x);
        sse += e; spl += e * hl[ct]; spa += e * ha[ct]; spt += e * ht[ct];
      }
#pragma unroll
      for (int o = 1; o < 16; o <<= 1) {
        sse += __shfl_xor(sse, o);
        spl += __shfl_xor(spl, o);
        spa += __shfl_xor(spa, o);
        spt += __shfl_xor(spt, o);
      }
      if (c4 == 0)
        redS[w][rt * 16 + q4 * 4 + reg] = (f32x4){sse, spl, spa, spt};
    }
  }
  __syncthreads();

  // ---- finalize on wave 0: one row per lane --------------------------------
  if (w == 0) {
    int row = lane;
    f32x4 t = (f32x4){0.f,0.f,0.f,0.f};
#pragma unroll
    for (int wc = 0; wc < 8; ++wc) t += redS[wc][row];
    float inv = 1.0f / t[0];
    int r = rt8 * 64 + row;
    float cl = tanhf(t[1] * inv + bld[0]) * wl1[r];
    float ca = tanhf(t[2] * inv + bad[0]) * wa1[r];
    float ctv = tanhf(t[3] * inv + btd[0]) * wt1[r];
#pragma unroll
    for (int o = 1; o < 64; o <<= 1) {
      cl += __shfl_xor(cl, o);
      ca += __shfl_xor(ca, o);
      ctv += __shfl_xor(ctv, o);
    }
    if (lane == 0) {
      float* sums = ws + OFF_SUM;
      atomicAdd(&sums[b * nL + l], cl);
      atomicAdd(&sums[nB * nL + b * nL + l], ca);
      atomicAdd(&sums[2 * nB * nL + b * nL + l], ctv);
    }
  }
}

// ---- K4: finalize heads ----------------------------------------------------
__global__ void k_final(const float* __restrict__ ws, float* __restrict__ out,
                        const float* __restrict__ bl1, const float* __restrict__ ba1,
                        const float* __restrict__ Wa2, const float* __restrict__ ba2,
                        const float* __restrict__ bt1, const float* __restrict__ Wt2,
                        const float* __restrict__ bt2) {
  __shared__ float abl[nB * nL], tbl[nB * nL];
  int t = threadIdx.x;
  const float* sl = ws + OFF_SUM;
  const float* sa = sl + nB * nL;
  const float* st = sa + nB * nL;
  if (t < nB * nL) {
    out[t] = sl[t] + bl1[0];
    abl[t] = tanhf(sa[t] + ba1[0]);
    tbl[t] = tanhf(st[t] + bt1[0]);
  }
  __syncthreads();
  for (int idx = t; idx < nB * 119; idx += 256) {
    int b = idx / 119, j = idx % 119;
    float a = ba2[j];
    for (int ll = 0; ll < nL; ++ll) a += Wa2[j * nL + ll] * abl[b * nL + ll];
    out[nB * nL + idx] = a;
  }
  for (int idx = t; idx < nB * 11; idx += 256) {
    int b = idx / 11, j = idx % 11;
    float a = bt2[j];
    for (int ll = 0; ll < nL; ++ll) a += Wt2[j * nL + ll] * tbl[b * nL + ll];
    out[nB * nL + nB * 119 + idx] = a;
  }
}

extern "C" void kernel_launch(void* const* d_in, const int* in_sizes, int n_in,
                              void* d_out, int out_size, void* d_ws, size_t ws_size,
                              hipStream_t stream) {
  (void)in_sizes; (void)n_in; (void)out_size; (void)ws_size;
  const float* outp = (const float*)d_in[0];
  const int*   mask = (const int*)d_in[1];
  const float* laws = (const float*)d_in[2];
  const float* Wq = (const float*)d_in[3];  const float* bq = (const float*)d_in[4];
  const float* Wk = (const float*)d_in[5];  const float* bk = (const float*)d_in[6];
  const float* Wv = (const float*)d_in[7];  const float* bv = (const float*)d_in[8];
  const float* wld = (const float*)d_in[9];  const float* bld = (const float*)d_in[10];
  const float* wl1 = (const float*)d_in[11]; const float* bl1 = (const float*)d_in[12];
  const float* wad = (const float*)d_in[13]; const float* bad = (const float*)d_in[14];
  const float* wa1 = (const float*)d_in[15]; const float* ba1 = (const float*)d_in[16];
  const float* Wa2 = (const float*)d_in[17]; const float* ba2 = (const float*)d_in[18];
  const float* wtd = (const float*)d_in[19]; const float* btd = (const float*)d_in[20];
  const float* wt1 = (const float*)d_in[21]; const float* bt1 = (const float*)d_in[22];
  const float* Wt2 = (const float*)d_in[23]; const float* bt2 = (const float*)d_in[24];
  float* ws = (float*)d_ws;
  float* fout = (float*)d_out;
  u16* kqB = (u16*)(ws + OFF_KQB);

  // 1) row-dots + consts + zero SUM + pack outp -> bf16
  k_prep<<<385, 256, 0, stream>>>(Wq, Wk, Wv, bq, bk, bv, wld, wad, wtd, outp, ws);
  // 2) M = Wq @ Wk^T (direct-frag MFMA) + chv
  k_mmM_chv<<<400, 256, 0, stream>>>(Wq, Wk, outp, ws);
  // 3) kq = outb @ M^T + qbk -> kqB frag layout
  k_mkq<<<dim3(12, 16), 256, 0, stream>>>(ws);
  // 4) fused scores + full-row softmax + heads
  k_attn<<<dim3(nB, 8, nL), 512, 0, stream>>>(laws, kqB, mask, ws,
                                              bld, wl1, bad, wa1, btd, wt1);
  // 5) output heads
  k_final<<<1, 256, 0, stream>>>(ws, fout, bl1, ba1, Wa2, ba2, bt1, Wt2, bt2);
}